// Round 3
// baseline (927.870 us; speedup 1.0000x reference)
//
#include <hip/hip_runtime.h>
#include <hip/hip_fp16.h>
#include <math.h>

#define NN 100000
#define EE 1600000
#define HH 64
#define LL 8
#define NBLK ((NN + 1023) / 1024)
#define NB128 ((NN + 127) / 128)
#define AGG_BLOCKS 2496

// binned scatter params
#define NPB 512                         // nodes per bucket (pow2)
#define BSH 9                           // log2(NPB)
#define NBUCK ((NN + NPB - 1) / NPB)    // 196
#define BIN_CHUNK 4096                  // edges per bin block (16/thread)

__device__ __forceinline__ float eluf(float x) { return x > 0.0f ? x : expm1f(x); }

// ================= CSR build =================

__global__ void count_edges_v2(const int* __restrict__ dst, int* __restrict__ counts) {
    int i = blockIdx.x * blockDim.x + threadIdx.x;
    if (i < EE) atomicAdd(&counts[dst[i]], 1);
}

__global__ void scan_block_v2(const int* __restrict__ counts, int* __restrict__ rp,
                              int* __restrict__ partial, float* __restrict__ dinv) {
    __shared__ int sm[256];
    const int t = threadIdx.x;
    const int base = blockIdx.x * 1024 + t * 4;
    int v0 = 0, v1 = 0, v2 = 0, v3 = 0;
    if (base + 0 < NN) v0 = counts[base + 0];
    if (base + 1 < NN) v1 = counts[base + 1];
    if (base + 2 < NN) v2 = counts[base + 2];
    if (base + 3 < NN) v3 = counts[base + 3];
    if (base + 0 < NN) dinv[base + 0] = rsqrtf((float)(v0 + 1));
    if (base + 1 < NN) dinv[base + 1] = rsqrtf((float)(v1 + 1));
    if (base + 2 < NN) dinv[base + 2] = rsqrtf((float)(v2 + 1));
    if (base + 3 < NN) dinv[base + 3] = rsqrtf((float)(v3 + 1));
    const int s = v0 + v1 + v2 + v3;
    sm[t] = s;
    __syncthreads();
    for (int off = 1; off < 256; off <<= 1) {
        int x = 0;
        if (t >= off) x = sm[t - off];
        __syncthreads();
        if (t >= off) sm[t] += x;
        __syncthreads();
    }
    int excl = sm[t] - s;
    if (t == 255) partial[blockIdx.x] = sm[255];
    if (base + 0 < NN) rp[base + 0] = excl;
    excl += v0;
    if (base + 1 < NN) rp[base + 1] = excl;
    excl += v1;
    if (base + 2 < NN) rp[base + 2] = excl;
    excl += v2;
    if (base + 3 < NN) rp[base + 3] = excl;
}

__global__ void scan_top_v2(int* partial) {
    __shared__ int sm[128];
    const int t = threadIdx.x;
    const int v = (t < NBLK) ? partial[t] : 0;
    sm[t] = v;
    __syncthreads();
    for (int off = 1; off < 128; off <<= 1) {
        int x = 0;
        if (t >= off) x = sm[t - off];
        __syncthreads();
        if (t >= off) sm[t] += x;
        __syncthreads();
    }
    if (t < NBLK) partial[t] = sm[t] - v;  // exclusive
}

__global__ void scan_add_v2(int* rp, const int* __restrict__ partial) {
    const int i = blockIdx.x * blockDim.x + threadIdx.x;
    if (i < NN) rp[i] += partial[i >> 10];
    else if (i == NN) rp[NN] = EE;
}

// ================= binned scatter =================
// R10: scatter_v2 wrote 107MB HBM for a 6.4MB payload (random 4B stores
// -> full-line writeback). Two-phase: (A) bin edges into 196 buckets of 512
// consecutive dst nodes (bucket regions ARE contiguous CSR ranges, base =
// rp[b<<9]); packed u32 payload = (dst&511)<<17 | src. (B) one block per
// bucket: rp + fill counters in LDS, scatter col within a hot 32KB window.
// Measured R2: replaced the 81us scatter; saved ~45us net.

__global__ __launch_bounds__(256) void bin_edges_v1(const int* __restrict__ src,
                                                    const int* __restrict__ dst,
                                                    const int* __restrict__ rp,
                                                    int* __restrict__ bfill,
                                                    unsigned* __restrict__ tmp) {
    __shared__ int hist[NBUCK];
    __shared__ int basei[NBUCK];
    __shared__ int rpb[NBUCK];
    __shared__ int cur[NBUCK];
    const int t = threadIdx.x;
    const int e0 = blockIdx.x * BIN_CHUNK;
    for (int b = t; b < NBUCK; b += 256) {
        hist[b] = 0;
        cur[b] = 0;
    }
    __syncthreads();
    int myd[16];
#pragma unroll
    for (int i = 0; i < 16; ++i) {
        const int e = e0 + i * 256 + t;
        int d = -1;
        if (e < EE) {
            d = dst[e];
            atomicAdd(&hist[d >> BSH], 1);
        }
        myd[i] = d;
    }
    __syncthreads();
    for (int b = t; b < NBUCK; b += 256) {
        const int h = hist[b];
        basei[b] = h ? atomicAdd(&bfill[b], h) : 0;
        rpb[b] = rp[b << BSH];
    }
    __syncthreads();
#pragma unroll
    for (int i = 0; i < 16; ++i) {
        const int e = e0 + i * 256 + t;
        if (e < EE) {
            const int d = myd[i];
            const int b = d >> BSH;
            const int slot = atomicAdd(&cur[b], 1);
            tmp[rpb[b] + basei[b] + slot] =
                ((unsigned)(d & (NPB - 1)) << 17) | (unsigned)src[e];
        }
    }
}

__global__ __launch_bounds__(512) void unbin_v1(const unsigned* __restrict__ tmp,
                                                const int* __restrict__ rp,
                                                int* __restrict__ col) {
    __shared__ int lrp[NPB];
    __shared__ int lfill[NPB];
    const int t = threadIdx.x;
    const int node0 = blockIdx.x << BSH;
    const int nodes = (NN - node0 < NPB) ? (NN - node0) : NPB;
    for (int i = t; i < nodes; i += 512) {
        lrp[i] = rp[node0 + i];
        lfill[i] = 0;
    }
    __syncthreads();
    const int lo = rp[node0];
    const int hi = rp[node0 + nodes];
    for (int e = lo + t; e < hi; e += 512) {
        const unsigned v = tmp[e];
        const int s = (int)(v & 0x1FFFFu);
        const int doff = (int)(v >> 17);
        const int pos = lrp[doff] + atomicAdd(&lfill[doff], 1);
        col[pos] = s;
    }
}

// zero sentinel row NN of both fp16 gather buffers (masked lanes gather row NN)
__global__ void init_sent_v2(__half* a, __half* b) {
    const int t = threadIdx.x;
    if (t < 64) a[(size_t)NN * HH + t] = __float2half(0.f);
    else b[(size_t)NN * HH + (t - 64)] = __float2half(0.f);
}

// ================= aggregation: s = 0.5*di*(sum h~[src] + h~[self]) + 0.5*x0 =================
// One wave per node. 8 groups x 8 lanes; each lane covers an 8-feature chunk via
// 16B fp16 loads; 32 edges per j-step -> 4 gather rows in flight per lane.
// R9 post-mortem: fusing into the GEMM block halved TLP for this latency-bound
// gather -> regressed; keep separate. Little's-law: ~4KB/wave in flight at
// ~30 waves/CU far exceeds BW*latency product -> near the random-gather
// machine limit (L1 miss path). No further lever without precision loss.

__global__ __launch_bounds__(256) void agg_v2(
    const int* __restrict__ rp, const int* __restrict__ col, const float* __restrict__ dinv,
    const __half* __restrict__ hin, const float* __restrict__ x0, float* __restrict__ sout) {
    const int lane = threadIdx.x & 63;
    const int g = lane >> 3;         // group 0..7
    const int fc = (lane & 7) << 3;  // feature chunk base
    const int wave = blockIdx.x * 4 + (threadIdx.x >> 6);
    const int nwaves = gridDim.x * 4;

    for (int node = wave; node < NN; node += nwaves) {
        const int start = rp[node], end = rp[node + 1];
        float acc[8] = {};
        for (int e = start; e < end; e += 64) {
            const int me = e + lane;
            const int c = (me < end) ? col[me] : NN;  // sentinel row NN is all-zero
            int nb = end - e;
            if (nb > 64) nb = 64;
            const int it = (nb + 31) >> 5;  // 32 edges per j-step
            for (int j = 0; j < it; ++j) {
                const int b = j * 32 + g;
                const int c0 = __shfl(c, b, 64);
                const int c1 = __shfl(c, b + 8, 64);
                const int c2 = __shfl(c, b + 16, 64);
                const int c3 = __shfl(c, b + 24, 64);
                float4 r0 = *(const float4*)(hin + ((size_t)c0 << 6) + fc);
                float4 r1 = *(const float4*)(hin + ((size_t)c1 << 6) + fc);
                float4 r2 = *(const float4*)(hin + ((size_t)c2 << 6) + fc);
                float4 r3 = *(const float4*)(hin + ((size_t)c3 << 6) + fc);
                const __half2* h0 = (const __half2*)&r0;
                const __half2* h1 = (const __half2*)&r1;
                const __half2* h2 = (const __half2*)&r2;
                const __half2* h3 = (const __half2*)&r3;
#pragma unroll
                for (int q = 0; q < 4; ++q) {
                    const float2 f0 = __half22float2(h0[q]);
                    const float2 f1 = __half22float2(h1[q]);
                    const float2 f2 = __half22float2(h2[q]);
                    const float2 f3 = __half22float2(h3[q]);
                    acc[2 * q] += (f0.x + f1.x) + (f2.x + f3.x);
                    acc[2 * q + 1] += (f0.y + f1.y) + (f2.y + f3.y);
                }
            }
        }
        // reduce the 8 groups (lane bits 3..5)
#pragma unroll
        for (int m = 8; m <= 32; m <<= 1)
#pragma unroll
            for (int q = 0; q < 8; ++q) acc[q] += __shfl_xor(acc[q], m, 64);
        if (g == 0) {  // lanes 0..7 hold full sums for chunks 0..7
            float4 r = *(const float4*)(hin + ((size_t)node << 6) + fc);
            const __half2* hh = (const __half2*)&r;
#pragma unroll
            for (int q = 0; q < 4; ++q) {
                const float2 f = __half22float2(hh[q]);
                acc[2 * q] += f.x;
                acc[2 * q + 1] += f.y;
            }
            const float di = dinv[node];
            const float4* xp = (const float4*)(x0 + ((size_t)node << 6) + fc);
            const float4 xa = xp[0], xb = xp[1];
            float4 oa, ob;
            oa.x = 0.5f * fmaf(di, acc[0], xa.x);
            oa.y = 0.5f * fmaf(di, acc[1], xa.y);
            oa.z = 0.5f * fmaf(di, acc[2], xa.z);
            oa.w = 0.5f * fmaf(di, acc[3], xa.w);
            ob.x = 0.5f * fmaf(di, acc[4], xb.x);
            ob.y = 0.5f * fmaf(di, acc[5], xb.y);
            ob.z = 0.5f * fmaf(di, acc[6], xb.z);
            ob.w = 0.5f * fmaf(di, acc[7], xb.w);
            float4* sp = (float4*)(sout + ((size_t)node << 6) + fc);
            sp[0] = oa;
            sp[1] = ob;
        }
    }
}

// ================= layer GEMM: o = s @ (beta*W + (1-beta)*I); h = elu(o)+o =================
// R11 theory: 4x4/thread tile ran at VALUBusy 40% (8 ds_read_b128 per 64 fma,
// 2.0 LDS-B/flop, ~2.5 waves/SIMD). New: 128x64 tile, each thread computes TWO
// 4x4 row-groups (rows ty*4+i and 64+ty*4+i) -> 12 ds_read per 128 fma
// (1.5 B/flop), 2x ILP. The two groups keep the 4-row-stride LDS pattern
// (stride 4*68 floats == bank+16 -> 2-way, free per m136); a single 8-row
// stride would be a 4-way conflict. LDS 51.2KB -> 3 blocks/CU.
// launch_bounds(256,3) caps VGPR ~168 (live est ~150); unroll 2 bounds the
// scheduler window (R8 spill lesson). WRITE_SIZE jump = spill = revert.

__global__ __launch_bounds__(256, 3) void lgemm_v4(const float* __restrict__ A,
                                                   const float* __restrict__ W,
                                                   const float* __restrict__ dinvp, float beta,
                                                   __half* __restrict__ out16,
                                                   float* __restrict__ out32, int w32) {
    __shared__ float ss[128][68];
    __shared__ float ws[64][64];
    const int t = threadIdx.x;
    const int row0 = blockIdx.x * 128;
    const int tx = t & 15, ty = t >> 4;
    float acc[2][4][4] = {};
    const float ob = 1.0f - beta;

#pragma unroll
    for (int i = 0; i < 8; ++i) {
        const int linear = t + i * 256;
        const int r = linear >> 4, q = linear & 15;
        const int grow = row0 + r;
        float4 v = make_float4(0.f, 0.f, 0.f, 0.f);
        if (grow < NN) v = *(const float4*)&A[(size_t)grow * 64 + q * 4];
        *(float4*)&ss[r][q * 4] = v;
    }
#pragma unroll
    for (int i = 0; i < 4; ++i) {
        const int linear = t + i * 256;
        const int r = linear >> 4, q = linear & 15;
        float4 v = *(const float4*)&W[(size_t)r * 64 + q * 4];
        v.x = v.x * beta + ((q * 4 + 0 == r) ? ob : 0.f);
        v.y = v.y * beta + ((q * 4 + 1 == r) ? ob : 0.f);
        v.z = v.z * beta + ((q * 4 + 2 == r) ? ob : 0.f);
        v.w = v.w * beta + ((q * 4 + 3 == r) ? ob : 0.f);
        *(float4*)&ws[r][q * 4] = v;
    }
    __syncthreads();
#pragma unroll 2
    for (int k = 0; k < 64; k += 4) {
        float4 a0[4], a1[4], bf[4];
#pragma unroll
        for (int i = 0; i < 4; ++i) {
            a0[i] = *(const float4*)&ss[ty * 4 + i][k];
            a1[i] = *(const float4*)&ss[64 + ty * 4 + i][k];
        }
#pragma unroll
        for (int j = 0; j < 4; ++j) bf[j] = *(const float4*)&ws[k + j][tx * 4];
        const float* A0 = (const float*)a0;
        const float* A1 = (const float*)a1;
        const float* B4 = (const float*)bf;
#pragma unroll
        for (int i = 0; i < 4; ++i)
#pragma unroll
            for (int kk = 0; kk < 4; ++kk)
#pragma unroll
                for (int j = 0; j < 4; ++j) {
                    acc[0][i][j] = fmaf(A0[i * 4 + kk], B4[kk * 4 + j], acc[0][i][j]);
                    acc[1][i][j] = fmaf(A1[i * 4 + kk], B4[kk * 4 + j], acc[1][i][j]);
                }
    }

#pragma unroll
    for (int h = 0; h < 2; ++h) {
#pragma unroll
        for (int i = 0; i < 4; ++i) {
            const int r = row0 + h * 64 + ty * 4 + i;
            if (r >= NN) continue;
            const float dv = dinvp[r];
            const float o0 = acc[h][i][0], o1 = acc[h][i][1];
            const float o2 = acc[h][i][2], o3 = acc[h][i][3];
            const float h0 = eluf(o0) + o0;
            const float h1 = eluf(o1) + o1;
            const float h2 = eluf(o2) + o2;
            const float h3 = eluf(o3) + o3;
            __half2* hp = (__half2*)&out16[(size_t)r * 64 + tx * 4];
            hp[0] = __floats2half2_rn(h0 * dv, h1 * dv);
            hp[1] = __floats2half2_rn(h2 * dv, h3 * dv);
            if (w32) {
                *(float4*)&out32[(size_t)r * 64 + tx * 4] = make_float4(h0, h1, h2, h3);
            }
        }
    }
}

// ================= dense GEMM for input/output layers (128x64 tile) =================
// MODE 0: out32 = elu(A@B + bias); out16 = half(dinv[r] * out32)   (KTOT=256)
// MODE 2: out32 = A@B + bias                                       (KTOT=64)

template <int KTOT, int MODE>
__global__ __launch_bounds__(256, 3) void gemm_v3(const float* __restrict__ A,
                                                  const float* __restrict__ B,
                                                  const float* __restrict__ bias,
                                                  const float* __restrict__ dinvp,
                                                  float* __restrict__ out32,
                                                  __half* __restrict__ out16) {
    __shared__ float ss[128][68];
    __shared__ float ws[64][64];
    const int t = threadIdx.x;
    const int row0 = blockIdx.x * 128;
    const int tx = t & 15, ty = t >> 4;
    float acc[2][4][4] = {};

    for (int kc = 0; kc < KTOT; kc += 64) {
#pragma unroll
        for (int i = 0; i < 8; ++i) {
            const int linear = t + i * 256;
            const int r = linear >> 4, q = linear & 15;
            const int grow = row0 + r;
            float4 v = make_float4(0.f, 0.f, 0.f, 0.f);
            if (grow < NN) v = *(const float4*)&A[(size_t)grow * KTOT + kc + q * 4];
            *(float4*)&ss[r][q * 4] = v;
        }
#pragma unroll
        for (int i = 0; i < 4; ++i) {
            const int linear = t + i * 256;
            const int r = linear >> 4, q = linear & 15;
            *(float4*)&ws[r][q * 4] = *(const float4*)&B[(size_t)(kc + r) * 64 + q * 4];
        }
        __syncthreads();
#pragma unroll 2
        for (int k = 0; k < 64; k += 4) {
            float4 a0[4], a1[4], bf[4];
#pragma unroll
            for (int i = 0; i < 4; ++i) {
                a0[i] = *(const float4*)&ss[ty * 4 + i][k];
                a1[i] = *(const float4*)&ss[64 + ty * 4 + i][k];
            }
#pragma unroll
            for (int j = 0; j < 4; ++j) bf[j] = *(const float4*)&ws[k + j][tx * 4];
            const float* A0 = (const float*)a0;
            const float* A1 = (const float*)a1;
            const float* B4 = (const float*)bf;
#pragma unroll
            for (int i = 0; i < 4; ++i)
#pragma unroll
                for (int kk = 0; kk < 4; ++kk)
#pragma unroll
                    for (int j = 0; j < 4; ++j) {
                        acc[0][i][j] = fmaf(A0[i * 4 + kk], B4[kk * 4 + j], acc[0][i][j]);
                        acc[1][i][j] = fmaf(A1[i * 4 + kk], B4[kk * 4 + j], acc[1][i][j]);
                    }
        }
        __syncthreads();
    }

#pragma unroll
    for (int h = 0; h < 2; ++h) {
#pragma unroll
        for (int i = 0; i < 4; ++i) {
            const int r = row0 + h * 64 + ty * 4 + i;
            if (r >= NN) continue;
            float4 o;
            float* op = (float*)&o;
#pragma unroll
            for (int j = 0; j < 4; ++j) {
                float xv = acc[h][i][j] + bias[tx * 4 + j];
                if (MODE == 0) xv = eluf(xv);
                op[j] = xv;
            }
            *(float4*)&out32[(size_t)r * 64 + tx * 4] = o;
            if (MODE == 0) {
                const float dv = dinvp[r];
                __half2* hp = (__half2*)&out16[(size_t)r * 64 + tx * 4];
                hp[0] = __floats2half2_rn(o.x * dv, o.y * dv);
                hp[1] = __floats2half2_rn(o.z * dv, o.w * dv);
            }
        }
    }
}

// ================= launch =================

extern "C" void kernel_launch(void* const* d_in, const int* in_sizes, int n_in, void* d_out,
                              int out_size, void* d_ws, size_t ws_size, hipStream_t stream) {
    const float* x = (const float*)d_in[0];
    const int* ei = (const int*)d_in[1];
    const float* w_in = (const float*)d_in[2];
    const float* b_in = (const float*)d_in[3];
    const float* w_layers = (const float*)d_in[4];
    const float* w_out = (const float*)d_in[5];
    const float* b_out = (const float*)d_in[6];
    float* out = (float*)d_out;

    char* p = (char*)d_ws;
    auto alloc = [&](size_t bytes) -> char* {
        char* r = p;
        p += (bytes + 255) & ~(size_t)255;
        return r;
    };
    int* counts = (int*)alloc((size_t)NN * 4);
    int* bfill = (int*)alloc((size_t)NBUCK * 4);
    int* rp = (int*)alloc((size_t)(NN + 1) * 4);
    int* partial = (int*)alloc(128 * 4);
    float* dinv = (float*)alloc((size_t)NN * 4);
    int* colA = (int*)alloc((size_t)EE * 4);
    unsigned* tmp = (unsigned*)alloc((size_t)EE * 4);         // binned packed edges
    float* x0 = (float*)alloc((size_t)NN * HH * 4);           // fp32 residual
    __half* x0h = (__half*)alloc((size_t)(NN + 1) * HH * 2);  // scaled gather buf A
    __half* hA = (__half*)alloc((size_t)(NN + 1) * HH * 2);   // scaled gather buf B
    float* sbuf = (float*)alloc((size_t)NN * HH * 4);         // fp32 s / final fp32 h

    const int* srcA = ei;
    const int* dstA = ei + EE;

    hipMemsetAsync(counts, 0, (size_t)NN * 4, stream);
    hipMemsetAsync(bfill, 0, (size_t)NBUCK * 4, stream);
    init_sent_v2<<<1, 128, 0, stream>>>(x0h, hA);
    count_edges_v2<<<(EE + 255) / 256, 256, 0, stream>>>(dstA, counts);
    scan_block_v2<<<NBLK, 256, 0, stream>>>(counts, rp, partial, dinv);
    scan_top_v2<<<1, 128, 0, stream>>>(partial);
    scan_add_v2<<<(NN + 1 + 255) / 256, 256, 0, stream>>>(rp, partial);
    bin_edges_v1<<<(EE + BIN_CHUNK - 1) / BIN_CHUNK, 256, 0, stream>>>(srcA, dstA, rp, bfill,
                                                                       tmp);
    unbin_v1<<<NBUCK, 512, 0, stream>>>(tmp, rp, colA);

    // x0 = elu(x @ w_in + b_in);  x0h = half(dinv * x0)
    gemm_v3<256, 0><<<NB128, 256, 0, stream>>>(x, w_in, b_in, dinv, x0, x0h);

    for (int l = 0; l < LL; ++l) {
        const float beta = (float)log(1.0 / (double)(l + 1) + 1.0);
        const __half* hin = (l & 1) ? hA : x0h;  // l=0 reads x0h
        __half* hout = (l & 1) ? x0h : hA;
        agg_v2<<<AGG_BLOCKS, 256, 0, stream>>>(rp, colA, dinv, hin, x0, sbuf);
        lgemm_v4<<<NB128, 256, 0, stream>>>(sbuf, w_layers + (size_t)l * 64 * 64, dinv,
                                            beta, hout, sbuf, l == LL - 1);
    }
    gemm_v3<64, 2><<<NB128, 256, 0, stream>>>(sbuf, w_out, b_out, nullptr, out, nullptr);
}

// Round 4
// 880.699 us; speedup vs baseline: 1.0536x; 1.0536x over previous
//
#include <hip/hip_runtime.h>
#include <hip/hip_fp16.h>
#include <math.h>

#define NN 100000
#define EE 1600000
#define HH 64
#define LL 8
#define NBLK ((NN + 1023) / 1024)
#define AGG_BLOCKS 2496

// binned scatter params
#define NPB 512                         // nodes per bucket (pow2)
#define BSH 9                           // log2(NPB)
#define NBUCK ((NN + NPB - 1) / NPB)    // 196
#define BIN_CHUNK 4096                  // edges per bin block (16/thread)

typedef _Float16 f16x8 __attribute__((ext_vector_type(8)));
typedef float f32x4 __attribute__((ext_vector_type(4)));

__device__ __forceinline__ float eluf(float x) { return x > 0.0f ? x : expm1f(x); }

// ================= CSR build =================

__global__ void count_edges_v2(const int* __restrict__ dst, int* __restrict__ counts) {
    int i = blockIdx.x * blockDim.x + threadIdx.x;
    if (i < EE) atomicAdd(&counts[dst[i]], 1);
}

__global__ void scan_block_v2(const int* __restrict__ counts, int* __restrict__ rp,
                              int* __restrict__ partial, float* __restrict__ dinv) {
    __shared__ int sm[256];
    const int t = threadIdx.x;
    const int base = blockIdx.x * 1024 + t * 4;
    int v0 = 0, v1 = 0, v2 = 0, v3 = 0;
    if (base + 0 < NN) v0 = counts[base + 0];
    if (base + 1 < NN) v1 = counts[base + 1];
    if (base + 2 < NN) v2 = counts[base + 2];
    if (base + 3 < NN) v3 = counts[base + 3];
    if (base + 0 < NN) dinv[base + 0] = rsqrtf((float)(v0 + 1));
    if (base + 1 < NN) dinv[base + 1] = rsqrtf((float)(v1 + 1));
    if (base + 2 < NN) dinv[base + 2] = rsqrtf((float)(v2 + 1));
    if (base + 3 < NN) dinv[base + 3] = rsqrtf((float)(v3 + 1));
    const int s = v0 + v1 + v2 + v3;
    sm[t] = s;
    __syncthreads();
    for (int off = 1; off < 256; off <<= 1) {
        int x = 0;
        if (t >= off) x = sm[t - off];
        __syncthreads();
        if (t >= off) sm[t] += x;
        __syncthreads();
    }
    int excl = sm[t] - s;
    if (t == 255) partial[blockIdx.x] = sm[255];
    if (base + 0 < NN) rp[base + 0] = excl;
    excl += v0;
    if (base + 1 < NN) rp[base + 1] = excl;
    excl += v1;
    if (base + 2 < NN) rp[base + 2] = excl;
    excl += v2;
    if (base + 3 < NN) rp[base + 3] = excl;
}

__global__ void scan_top_v2(int* partial) {
    __shared__ int sm[128];
    const int t = threadIdx.x;
    const int v = (t < NBLK) ? partial[t] : 0;
    sm[t] = v;
    __syncthreads();
    for (int off = 1; off < 128; off <<= 1) {
        int x = 0;
        if (t >= off) x = sm[t - off];
        __syncthreads();
        if (t >= off) sm[t] += x;
        __syncthreads();
    }
    if (t < NBLK) partial[t] = sm[t] - v;  // exclusive
}

__global__ void scan_add_v2(int* rp, const int* __restrict__ partial) {
    const int i = blockIdx.x * blockDim.x + threadIdx.x;
    if (i < NN) rp[i] += partial[i >> 10];
    else if (i == NN) rp[NN] = EE;
}

// ================= binned scatter =================
// R10: scatter_v2 wrote 107MB HBM for a 6.4MB payload. Two-phase binning
// keeps writes in hot windows. Measured R2: saved ~45us net.

__global__ __launch_bounds__(256) void bin_edges_v1(const int* __restrict__ src,
                                                    const int* __restrict__ dst,
                                                    const int* __restrict__ rp,
                                                    int* __restrict__ bfill,
                                                    unsigned* __restrict__ tmp) {
    __shared__ int hist[NBUCK];
    __shared__ int basei[NBUCK];
    __shared__ int rpb[NBUCK];
    __shared__ int cur[NBUCK];
    const int t = threadIdx.x;
    const int e0 = blockIdx.x * BIN_CHUNK;
    for (int b = t; b < NBUCK; b += 256) {
        hist[b] = 0;
        cur[b] = 0;
    }
    __syncthreads();
    int myd[16];
#pragma unroll
    for (int i = 0; i < 16; ++i) {
        const int e = e0 + i * 256 + t;
        int d = -1;
        if (e < EE) {
            d = dst[e];
            atomicAdd(&hist[d >> BSH], 1);
        }
        myd[i] = d;
    }
    __syncthreads();
    for (int b = t; b < NBUCK; b += 256) {
        const int h = hist[b];
        basei[b] = h ? atomicAdd(&bfill[b], h) : 0;
        rpb[b] = rp[b << BSH];
    }
    __syncthreads();
#pragma unroll
    for (int i = 0; i < 16; ++i) {
        const int e = e0 + i * 256 + t;
        if (e < EE) {
            const int d = myd[i];
            const int b = d >> BSH;
            const int slot = atomicAdd(&cur[b], 1);
            tmp[rpb[b] + basei[b] + slot] =
                ((unsigned)(d & (NPB - 1)) << 17) | (unsigned)src[e];
        }
    }
}

__global__ __launch_bounds__(512) void unbin_v1(const unsigned* __restrict__ tmp,
                                                const int* __restrict__ rp,
                                                int* __restrict__ col) {
    __shared__ int lrp[NPB];
    __shared__ int lfill[NPB];
    const int t = threadIdx.x;
    const int node0 = blockIdx.x << BSH;
    const int nodes = (NN - node0 < NPB) ? (NN - node0) : NPB;
    for (int i = t; i < nodes; i += 512) {
        lrp[i] = rp[node0 + i];
        lfill[i] = 0;
    }
    __syncthreads();
    const int lo = rp[node0];
    const int hi = rp[node0 + nodes];
    for (int e = lo + t; e < hi; e += 512) {
        const unsigned v = tmp[e];
        const int s = (int)(v & 0x1FFFFu);
        const int doff = (int)(v >> 17);
        const int pos = lrp[doff] + atomicAdd(&lfill[doff], 1);
        col[pos] = s;
    }
}

// zero sentinel row NN of both fp16 gather buffers (masked lanes gather row NN)
__global__ void init_sent_v2(__half* a, __half* b) {
    const int t = threadIdx.x;
    if (t < 64) a[(size_t)NN * HH + t] = __float2half(0.f);
    else b[(size_t)NN * HH + (t - 64)] = __float2half(0.f);
}

// w_in [256][64] fp32 -> wt [64][256] fp16 (transposed, for MFMA B-fragments)
__global__ void conv_w_v1(const float* __restrict__ w, __half* __restrict__ wt) {
    const int t = threadIdx.x;  // 256
    const int c = t & 63;
    const int k0 = (t >> 6) * 64;
    for (int k = 0; k < 64; ++k)
        wt[(size_t)c * 256 + k0 + k] = __float2half(w[(size_t)(k0 + k) * 64 + c]);
}

// ================= aggregation: s = 0.5*di*(sum h~[src] + h~[self]) + 0.5*x0 =================
// One wave per node; grid-stride for degree balance (R9: fusing into GEMM
// block halved TLP and regressed; keep separate).

__global__ __launch_bounds__(256) void agg_v2(
    const int* __restrict__ rp, const int* __restrict__ col, const float* __restrict__ dinv,
    const __half* __restrict__ hin, const float* __restrict__ x0, float* __restrict__ sout) {
    const int lane = threadIdx.x & 63;
    const int g = lane >> 3;         // group 0..7
    const int fc = (lane & 7) << 3;  // feature chunk base
    const int wave = blockIdx.x * 4 + (threadIdx.x >> 6);
    const int nwaves = gridDim.x * 4;

    for (int node = wave; node < NN; node += nwaves) {
        const int start = rp[node], end = rp[node + 1];
        float acc[8] = {};
        for (int e = start; e < end; e += 64) {
            const int me = e + lane;
            const int c = (me < end) ? col[me] : NN;  // sentinel row NN is all-zero
            int nb = end - e;
            if (nb > 64) nb = 64;
            const int it = (nb + 31) >> 5;  // 32 edges per j-step
            for (int j = 0; j < it; ++j) {
                const int b = j * 32 + g;
                const int c0 = __shfl(c, b, 64);
                const int c1 = __shfl(c, b + 8, 64);
                const int c2 = __shfl(c, b + 16, 64);
                const int c3 = __shfl(c, b + 24, 64);
                float4 r0 = *(const float4*)(hin + ((size_t)c0 << 6) + fc);
                float4 r1 = *(const float4*)(hin + ((size_t)c1 << 6) + fc);
                float4 r2 = *(const float4*)(hin + ((size_t)c2 << 6) + fc);
                float4 r3 = *(const float4*)(hin + ((size_t)c3 << 6) + fc);
                const __half2* h0 = (const __half2*)&r0;
                const __half2* h1 = (const __half2*)&r1;
                const __half2* h2 = (const __half2*)&r2;
                const __half2* h3 = (const __half2*)&r3;
#pragma unroll
                for (int q = 0; q < 4; ++q) {
                    const float2 f0 = __half22float2(h0[q]);
                    const float2 f1 = __half22float2(h1[q]);
                    const float2 f2 = __half22float2(h2[q]);
                    const float2 f3 = __half22float2(h3[q]);
                    acc[2 * q] += (f0.x + f1.x) + (f2.x + f3.x);
                    acc[2 * q + 1] += (f0.y + f1.y) + (f2.y + f3.y);
                }
            }
        }
        // reduce the 8 groups (lane bits 3..5)
#pragma unroll
        for (int m = 8; m <= 32; m <<= 1)
#pragma unroll
            for (int q = 0; q < 8; ++q) acc[q] += __shfl_xor(acc[q], m, 64);
        if (g == 0) {  // lanes 0..7 hold full sums for chunks 0..7
            float4 r = *(const float4*)(hin + ((size_t)node << 6) + fc);
            const __half2* hh = (const __half2*)&r;
#pragma unroll
            for (int q = 0; q < 4; ++q) {
                const float2 f = __half22float2(hh[q]);
                acc[2 * q] += f.x;
                acc[2 * q + 1] += f.y;
            }
            const float di = dinv[node];
            const float4* xp = (const float4*)(x0 + ((size_t)node << 6) + fc);
            const float4 xa = xp[0], xb = xp[1];
            float4 oa, ob;
            oa.x = 0.5f * fmaf(di, acc[0], xa.x);
            oa.y = 0.5f * fmaf(di, acc[1], xa.y);
            oa.z = 0.5f * fmaf(di, acc[2], xa.z);
            oa.w = 0.5f * fmaf(di, acc[3], xa.w);
            ob.x = 0.5f * fmaf(di, acc[4], xb.x);
            ob.y = 0.5f * fmaf(di, acc[5], xb.y);
            ob.z = 0.5f * fmaf(di, acc[6], xb.z);
            ob.w = 0.5f * fmaf(di, acc[7], xb.w);
            float4* sp = (float4*)(sout + ((size_t)node << 6) + fc);
            sp[0] = oa;
            sp[1] = ob;
        }
    }
}

// ================= MFMA input GEMM =================
// R12: fp32 4x4-tile GEMM was latency/issue-bound at 77us (VALU floor 21us,
// VALUBusy 40%). R3's bigger-tile attempt REGRESSED (103us, occ 19%): the
// kernel is latency-bound; occupancy and grid size matter more than ILP.
// MFMA route: 3.28 GFLOP -> ~1.6us of matrix-pipe. x staged to LDS as fp16
// (error ~5e-4 abs over K=256, 30x below current absmax); w_in pre-transposed
// to fp16 wt[64][256] so B-frags are contiguous 16B loads from a hot 32KB
// table. Layouts: C/D col=lane&15,row=(lane>>4)*4+reg (doc-verified);
// A row=lane&15, B col=lane&15, shared k-map (k-permutation cancels A vs B).

__global__ __launch_bounds__(256, 4) void mgemm_in_v1(
    const float* __restrict__ A, const __half* __restrict__ wt,
    const float* __restrict__ bias, const float* __restrict__ dinvp,
    float* __restrict__ out32, __half* __restrict__ out16) {
    __shared__ __half sh[64][264];
    const int t = threadIdx.x;
    const int row0 = blockIdx.x * 64;

    // stage x tile (64 rows x 256 k) as fp16
#pragma unroll
    for (int i = 0; i < 16; ++i) {
        const int linear = t + i * 256;  // 0..4095, 64 float4 per row
        const int r = linear >> 6;
        const int q = linear & 63;
        const int grow = row0 + r;
        float4 v = make_float4(0.f, 0.f, 0.f, 0.f);
        if (grow < NN) v = *(const float4*)&A[(size_t)grow * 256 + q * 4];
        __half2* dst = (__half2*)&sh[r][q * 4];
        dst[0] = __floats2half2_rn(v.x, v.y);
        dst[1] = __floats2half2_rn(v.z, v.w);
    }
    __syncthreads();

    const int lane = t & 63;
    const int w = t >> 6;  // wave 0..3 -> rows [w*16, w*16+16)
    const int la = lane & 15, lg = lane >> 4;
    f32x4 acc[4] = {};
    const __half* arow = &sh[w * 16 + la][0];
#pragma unroll
    for (int kc = 0; kc < 8; ++kc) {
        const int k0 = kc * 32 + lg * 8;
        const f16x8 a = *(const f16x8*)&arow[k0];
#pragma unroll
        for (int tt = 0; tt < 4; ++tt) {
            const f16x8 b = *(const f16x8*)&wt[(size_t)(la + 16 * tt) * 256 + k0];
            acc[tt] = __builtin_amdgcn_mfma_f32_16x16x32_f16(a, b, acc[tt], 0, 0, 0);
        }
    }

    // epilogue: o = elu(acc + bias); out32 = o; out16 = half(o * dinv)
#pragma unroll
    for (int i = 0; i < 4; ++i) {
        const int r = row0 + w * 16 + lg * 4 + i;
        if (r >= NN) continue;
        const float dv = dinvp[r];
#pragma unroll
        for (int tt = 0; tt < 4; ++tt) {
            const int c = la + 16 * tt;
            float o = acc[tt][i] + bias[c];
            o = eluf(o);
            out32[(size_t)r * 64 + c] = o;
            out16[(size_t)r * 64 + c] = __float2half(o * dv);
        }
    }
}

// ================= layer GEMM (R2-proven 64x64 shape) =================
// R3 post-mortem: 128-row tile cut occupancy 4->3 blk/CU and grid 1563->782;
// latency-bound kernel regressed 27%. Keep 64x64 / 4 blk/CU.

__global__ __launch_bounds__(256, 4) void lgemm_v3(const float* __restrict__ A,
                                                   const float* __restrict__ W,
                                                   const float* __restrict__ dinvp, float beta,
                                                   __half* __restrict__ out16,
                                                   float* __restrict__ out32, int w32) {
    __shared__ float ss[64][68];
    __shared__ float ws[64][64];
    const int t = threadIdx.x;
    const int row0 = blockIdx.x * 64;
    const int tx = t & 15, ty = t >> 4;
    float acc[4][4] = {};
    const float ob = 1.0f - beta;

#pragma unroll
    for (int i = 0; i < 4; ++i) {
        const int linear = t + i * 256;
        const int r = linear >> 4, q = linear & 15;
        const int grow = row0 + r;
        float4 v = make_float4(0.f, 0.f, 0.f, 0.f);
        if (grow < NN) v = *(const float4*)&A[(size_t)grow * 64 + q * 4];
        *(float4*)&ss[r][q * 4] = v;
    }
#pragma unroll
    for (int i = 0; i < 4; ++i) {
        const int linear = t + i * 256;
        const int r = linear >> 4, q = linear & 15;
        float4 v = *(const float4*)&W[(size_t)r * 64 + q * 4];
        v.x = v.x * beta + ((q * 4 + 0 == r) ? ob : 0.f);
        v.y = v.y * beta + ((q * 4 + 1 == r) ? ob : 0.f);
        v.z = v.z * beta + ((q * 4 + 2 == r) ? ob : 0.f);
        v.w = v.w * beta + ((q * 4 + 3 == r) ? ob : 0.f);
        *(float4*)&ws[r][q * 4] = v;
    }
    __syncthreads();
#pragma unroll 4
    for (int k = 0; k < 64; k += 4) {
        float4 af[4], bf[4];
        af[0] = *(const float4*)&ss[ty * 4 + 0][k];
        af[1] = *(const float4*)&ss[ty * 4 + 1][k];
        af[2] = *(const float4*)&ss[ty * 4 + 2][k];
        af[3] = *(const float4*)&ss[ty * 4 + 3][k];
        bf[0] = *(const float4*)&ws[k + 0][tx * 4];
        bf[1] = *(const float4*)&ws[k + 1][tx * 4];
        bf[2] = *(const float4*)&ws[k + 2][tx * 4];
        bf[3] = *(const float4*)&ws[k + 3][tx * 4];
        const float* A4 = (const float*)af;
        const float* B4 = (const float*)bf;
#pragma unroll
        for (int i = 0; i < 4; ++i)
#pragma unroll
            for (int kk = 0; kk < 4; ++kk)
#pragma unroll
                for (int j = 0; j < 4; ++j)
                    acc[i][j] = fmaf(A4[i * 4 + kk], B4[kk * 4 + j], acc[i][j]);
    }

#pragma unroll
    for (int i = 0; i < 4; ++i) {
        const int r = row0 + ty * 4 + i;
        if (r >= NN) continue;
        const float dv = dinvp[r];
        const float o0 = acc[i][0], o1 = acc[i][1], o2 = acc[i][2], o3 = acc[i][3];
        const float h0 = eluf(o0) + o0;
        const float h1 = eluf(o1) + o1;
        const float h2 = eluf(o2) + o2;
        const float h3 = eluf(o3) + o3;
        __half2* hp = (__half2*)&out16[(size_t)r * 64 + tx * 4];
        hp[0] = __floats2half2_rn(h0 * dv, h1 * dv);
        hp[1] = __floats2half2_rn(h2 * dv, h3 * dv);
        if (w32) {
            *(float4*)&out32[(size_t)r * 64 + tx * 4] = make_float4(h0, h1, h2, h3);
        }
    }
}

// ================= dense GEMM for output layer (R2-proven shape) =================
// MODE 2: out32 = A@B + bias    (KTOT=64)

template <int KTOT, int MODE>
__global__ __launch_bounds__(256, 4) void gemm_v2(const float* __restrict__ A,
                                                  const float* __restrict__ B,
                                                  const float* __restrict__ bias,
                                                  const float* __restrict__ dinvp,
                                                  float* __restrict__ out32,
                                                  __half* __restrict__ out16) {
    __shared__ float ss[64][68];
    __shared__ float ws[64][64];
    const int t = threadIdx.x;
    const int row0 = blockIdx.x * 64;
    const int tx = t & 15, ty = t >> 4;
    float acc[4][4] = {};

    for (int kc = 0; kc < KTOT; kc += 64) {
#pragma unroll
        for (int i = 0; i < 4; ++i) {
            const int linear = t + i * 256;
            const int r = linear >> 4, q = linear & 15;
            const int grow = row0 + r;
            float4 v = make_float4(0.f, 0.f, 0.f, 0.f);
            if (grow < NN) v = *(const float4*)&A[(size_t)grow * KTOT + kc + q * 4];
            *(float4*)&ss[r][q * 4] = v;
        }
#pragma unroll
        for (int i = 0; i < 4; ++i) {
            const int linear = t + i * 256;
            const int r = linear >> 4, q = linear & 15;
            *(float4*)&ws[r][q * 4] = *(const float4*)&B[(size_t)(kc + r) * 64 + q * 4];
        }
        __syncthreads();
#pragma unroll 4
        for (int k = 0; k < 64; k += 4) {
            float4 af[4], bf[4];
            af[0] = *(const float4*)&ss[ty * 4 + 0][k];
            af[1] = *(const float4*)&ss[ty * 4 + 1][k];
            af[2] = *(const float4*)&ss[ty * 4 + 2][k];
            af[3] = *(const float4*)&ss[ty * 4 + 3][k];
            bf[0] = *(const float4*)&ws[k + 0][tx * 4];
            bf[1] = *(const float4*)&ws[k + 1][tx * 4];
            bf[2] = *(const float4*)&ws[k + 2][tx * 4];
            bf[3] = *(const float4*)&ws[k + 3][tx * 4];
            const float* A4 = (const float*)af;
            const float* B4 = (const float*)bf;
#pragma unroll
            for (int i = 0; i < 4; ++i)
#pragma unroll
                for (int kk = 0; kk < 4; ++kk)
#pragma unroll
                    for (int j = 0; j < 4; ++j)
                        acc[i][j] = fmaf(A4[i * 4 + kk], B4[kk * 4 + j], acc[i][j]);
        }
        __syncthreads();
    }

#pragma unroll
    for (int i = 0; i < 4; ++i) {
        const int r = row0 + ty * 4 + i;
        if (r >= NN) continue;
        float4 o;
        float* op = (float*)&o;
#pragma unroll
        for (int j = 0; j < 4; ++j) {
            float xv = acc[i][j] + bias[tx * 4 + j];
            if (MODE == 0) xv = eluf(xv);
            op[j] = xv;
        }
        *(float4*)&out32[(size_t)r * 64 + tx * 4] = o;
        if (MODE == 0) {
            const float dv = dinvp[r];
            __half2* hp = (__half2*)&out16[(size_t)r * 64 + tx * 4];
            hp[0] = __floats2half2_rn(o.x * dv, o.y * dv);
            hp[1] = __floats2half2_rn(o.z * dv, o.w * dv);
        }
    }
}

// ================= launch =================

extern "C" void kernel_launch(void* const* d_in, const int* in_sizes, int n_in, void* d_out,
                              int out_size, void* d_ws, size_t ws_size, hipStream_t stream) {
    const float* x = (const float*)d_in[0];
    const int* ei = (const int*)d_in[1];
    const float* w_in = (const float*)d_in[2];
    const float* b_in = (const float*)d_in[3];
    const float* w_layers = (const float*)d_in[4];
    const float* w_out = (const float*)d_in[5];
    const float* b_out = (const float*)d_in[6];
    float* out = (float*)d_out;

    char* p = (char*)d_ws;
    auto alloc = [&](size_t bytes) -> char* {
        char* r = p;
        p += (bytes + 255) & ~(size_t)255;
        return r;
    };
    int* counts = (int*)alloc((size_t)NN * 4);
    int* bfill = (int*)alloc((size_t)NBUCK * 4);
    int* rp = (int*)alloc((size_t)(NN + 1) * 4);
    int* partial = (int*)alloc(128 * 4);
    float* dinv = (float*)alloc((size_t)NN * 4);
    int* colA = (int*)alloc((size_t)EE * 4);
    unsigned* tmp = (unsigned*)alloc((size_t)EE * 4);         // binned packed edges
    float* x0 = (float*)alloc((size_t)NN * HH * 4);           // fp32 residual
    __half* x0h = (__half*)alloc((size_t)(NN + 1) * HH * 2);  // scaled gather buf A
    __half* hA = (__half*)alloc((size_t)(NN + 1) * HH * 2);   // scaled gather buf B
    float* sbuf = (float*)alloc((size_t)NN * HH * 4);         // fp32 s / final fp32 h
    __half* wt = (__half*)alloc((size_t)64 * 256 * 2);        // w_in^T fp16

    const int* srcA = ei;
    const int* dstA = ei + EE;

    hipMemsetAsync(counts, 0, (size_t)NN * 4, stream);
    hipMemsetAsync(bfill, 0, (size_t)NBUCK * 4, stream);
    init_sent_v2<<<1, 128, 0, stream>>>(x0h, hA);
    conv_w_v1<<<1, 256, 0, stream>>>(w_in, wt);
    count_edges_v2<<<(EE + 255) / 256, 256, 0, stream>>>(dstA, counts);
    scan_block_v2<<<NBLK, 256, 0, stream>>>(counts, rp, partial, dinv);
    scan_top_v2<<<1, 128, 0, stream>>>(partial);
    scan_add_v2<<<(NN + 1 + 255) / 256, 256, 0, stream>>>(rp, partial);
    bin_edges_v1<<<(EE + BIN_CHUNK - 1) / BIN_CHUNK, 256, 0, stream>>>(srcA, dstA, rp, bfill,
                                                                       tmp);
    unbin_v1<<<NBUCK, 512, 0, stream>>>(tmp, rp, colA);

    // x0 = elu(x @ w_in + b_in);  x0h = half(dinv * x0)   [MFMA]
    mgemm_in_v1<<<(NN + 63) / 64, 256, 0, stream>>>(x, wt, b_in, dinv, x0, x0h);

    for (int l = 0; l < LL; ++l) {
        const float beta = (float)log(1.0 / (double)(l + 1) + 1.0);
        const __half* hin = (l & 1) ? hA : x0h;  // l=0 reads x0h
        __half* hout = (l & 1) ? x0h : hA;
        agg_v2<<<AGG_BLOCKS, 256, 0, stream>>>(rp, colA, dinv, hin, x0, sbuf);
        lgemm_v3<<<(NN + 63) / 64, 256, 0, stream>>>(sbuf, w_layers + (size_t)l * 64 * 64, dinv,
                                                     beta, hout, sbuf, l == LL - 1);
    }
    gemm_v2<64, 2><<<(NN + 63) / 64, 256, 0, stream>>>(sbuf, w_out, b_out, nullptr, out, nullptr);
}

// Round 5
// 850.115 us; speedup vs baseline: 1.0915x; 1.0360x over previous
//
#include <hip/hip_runtime.h>
#include <hip/hip_fp16.h>
#include <math.h>

#define NN 100000
#define EE 1600000
#define HH 64
#define LL 8
#define NBLK ((NN + 1023) / 1024)
#define AGG_BLOCKS 2496

// binned scatter params
#define NPB 512                         // nodes per bucket (pow2)
#define BSH 9                           // log2(NPB)
#define NBUCK ((NN + NPB - 1) / NPB)    // 196
#define BIN_CHUNK 4096                  // edges per bin block (16/thread)

typedef _Float16 f16x8 __attribute__((ext_vector_type(8)));
typedef float f32x4 __attribute__((ext_vector_type(4)));

__device__ __forceinline__ float eluf(float x) { return x > 0.0f ? x : expm1f(x); }

// ================= CSR build =================

__global__ void count_edges_v2(const int* __restrict__ dst, int* __restrict__ counts) {
    int i = blockIdx.x * blockDim.x + threadIdx.x;
    if (i < EE) atomicAdd(&counts[dst[i]], 1);
}

__global__ void scan_block_v2(const int* __restrict__ counts, int* __restrict__ rp,
                              int* __restrict__ partial, float* __restrict__ dinv) {
    __shared__ int sm[256];
    const int t = threadIdx.x;
    const int base = blockIdx.x * 1024 + t * 4;
    int v0 = 0, v1 = 0, v2 = 0, v3 = 0;
    if (base + 0 < NN) v0 = counts[base + 0];
    if (base + 1 < NN) v1 = counts[base + 1];
    if (base + 2 < NN) v2 = counts[base + 2];
    if (base + 3 < NN) v3 = counts[base + 3];
    if (base + 0 < NN) dinv[base + 0] = rsqrtf((float)(v0 + 1));
    if (base + 1 < NN) dinv[base + 1] = rsqrtf((float)(v1 + 1));
    if (base + 2 < NN) dinv[base + 2] = rsqrtf((float)(v2 + 1));
    if (base + 3 < NN) dinv[base + 3] = rsqrtf((float)(v3 + 1));
    const int s = v0 + v1 + v2 + v3;
    sm[t] = s;
    __syncthreads();
    for (int off = 1; off < 256; off <<= 1) {
        int x = 0;
        if (t >= off) x = sm[t - off];
        __syncthreads();
        if (t >= off) sm[t] += x;
        __syncthreads();
    }
    int excl = sm[t] - s;
    if (t == 255) partial[blockIdx.x] = sm[255];
    if (base + 0 < NN) rp[base + 0] = excl;
    excl += v0;
    if (base + 1 < NN) rp[base + 1] = excl;
    excl += v1;
    if (base + 2 < NN) rp[base + 2] = excl;
    excl += v2;
    if (base + 3 < NN) rp[base + 3] = excl;
}

__global__ void scan_top_v2(int* partial) {
    __shared__ int sm[128];
    const int t = threadIdx.x;
    const int v = (t < NBLK) ? partial[t] : 0;
    sm[t] = v;
    __syncthreads();
    for (int off = 1; off < 128; off <<= 1) {
        int x = 0;
        if (t >= off) x = sm[t - off];
        __syncthreads();
        if (t >= off) sm[t] += x;
        __syncthreads();
    }
    if (t < NBLK) partial[t] = sm[t] - v;  // exclusive
}

__global__ void scan_add_v2(int* rp, const int* __restrict__ partial) {
    const int i = blockIdx.x * blockDim.x + threadIdx.x;
    if (i < NN) rp[i] += partial[i >> 10];
    else if (i == NN) rp[NN] = EE;
}

// ================= binned scatter =================
// R10: scatter_v2 wrote 107MB HBM for a 6.4MB payload. Two-phase binning
// keeps writes in hot windows. Measured R2: saved ~45us net.

__global__ __launch_bounds__(256) void bin_edges_v1(const int* __restrict__ src,
                                                    const int* __restrict__ dst,
                                                    const int* __restrict__ rp,
                                                    int* __restrict__ bfill,
                                                    unsigned* __restrict__ tmp) {
    __shared__ int hist[NBUCK];
    __shared__ int basei[NBUCK];
    __shared__ int rpb[NBUCK];
    __shared__ int cur[NBUCK];
    const int t = threadIdx.x;
    const int e0 = blockIdx.x * BIN_CHUNK;
    for (int b = t; b < NBUCK; b += 256) {
        hist[b] = 0;
        cur[b] = 0;
    }
    __syncthreads();
    int myd[16];
#pragma unroll
    for (int i = 0; i < 16; ++i) {
        const int e = e0 + i * 256 + t;
        int d = -1;
        if (e < EE) {
            d = dst[e];
            atomicAdd(&hist[d >> BSH], 1);
        }
        myd[i] = d;
    }
    __syncthreads();
    for (int b = t; b < NBUCK; b += 256) {
        const int h = hist[b];
        basei[b] = h ? atomicAdd(&bfill[b], h) : 0;
        rpb[b] = rp[b << BSH];
    }
    __syncthreads();
#pragma unroll
    for (int i = 0; i < 16; ++i) {
        const int e = e0 + i * 256 + t;
        if (e < EE) {
            const int d = myd[i];
            const int b = d >> BSH;
            const int slot = atomicAdd(&cur[b], 1);
            tmp[rpb[b] + basei[b] + slot] =
                ((unsigned)(d & (NPB - 1)) << 17) | (unsigned)src[e];
        }
    }
}

__global__ __launch_bounds__(512) void unbin_v1(const unsigned* __restrict__ tmp,
                                                const int* __restrict__ rp,
                                                int* __restrict__ col) {
    __shared__ int lrp[NPB];
    __shared__ int lfill[NPB];
    const int t = threadIdx.x;
    const int node0 = blockIdx.x << BSH;
    const int nodes = (NN - node0 < NPB) ? (NN - node0) : NPB;
    for (int i = t; i < nodes; i += 512) {
        lrp[i] = rp[node0 + i];
        lfill[i] = 0;
    }
    __syncthreads();
    const int lo = rp[node0];
    const int hi = rp[node0 + nodes];
    for (int e = lo + t; e < hi; e += 512) {
        const unsigned v = tmp[e];
        const int s = (int)(v & 0x1FFFFu);
        const int doff = (int)(v >> 17);
        const int pos = lrp[doff] + atomicAdd(&lfill[doff], 1);
        col[pos] = s;
    }
}

// zero sentinel row NN of both fp16 gather buffers (masked lanes gather row NN)
__global__ void init_sent_v2(__half* a, __half* b) {
    const int t = threadIdx.x;
    if (t < 64) a[(size_t)NN * HH + t] = __float2half(0.f);
    else b[(size_t)NN * HH + (t - 64)] = __float2half(0.f);
}

// w_in [256][64] fp32 -> wt [64][256] fp16 (transposed, for MFMA B-fragments)
__global__ void conv_w_v1(const float* __restrict__ w, __half* __restrict__ wt) {
    const int t = threadIdx.x;  // 256
    const int c = t & 63;
    const int k0 = (t >> 6) * 64;
    for (int k = 0; k < 64; ++k)
        wt[(size_t)c * 256 + k0 + k] = __float2half(w[(size_t)(k0 + k) * 64 + c]);
}

// per-layer (beta_l * W_l)^T as fp16: btab[l][c][k] = beta_l * W_l[k][c]
// NOTE: identity term is NOT folded in (added exactly in fp32 in lgemm_v5 epilogue).
__global__ void conv_wbl_v1(const float* __restrict__ w_layers, __half* __restrict__ btab) {
    const int l = blockIdx.x;
    const float beta = logf(1.0f / (float)(l + 1) + 1.0f);
    const float* W = w_layers + (size_t)l * 64 * 64;
    __half* wt = btab + (size_t)l * 64 * 64;
    const int t = threadIdx.x;     // 256
    const int c = t & 63;          // output col
    const int k0 = (t >> 6) * 16;  // 16 k each
    for (int k = k0; k < k0 + 16; ++k)
        wt[(size_t)c * 64 + k] = __float2half(beta * W[(size_t)k * 64 + c]);
}

// ================= aggregation: s = 0.5*di*(sum h~[src] + h~[self]) + 0.5*x0 =================
// One wave per node; grid-stride for degree balance (R9: fusing into GEMM
// block halved TLP and regressed; keep separate).

__global__ __launch_bounds__(256) void agg_v2(
    const int* __restrict__ rp, const int* __restrict__ col, const float* __restrict__ dinv,
    const __half* __restrict__ hin, const float* __restrict__ x0, float* __restrict__ sout) {
    const int lane = threadIdx.x & 63;
    const int g = lane >> 3;         // group 0..7
    const int fc = (lane & 7) << 3;  // feature chunk base
    const int wave = blockIdx.x * 4 + (threadIdx.x >> 6);
    const int nwaves = gridDim.x * 4;

    for (int node = wave; node < NN; node += nwaves) {
        const int start = rp[node], end = rp[node + 1];
        float acc[8] = {};
        for (int e = start; e < end; e += 64) {
            const int me = e + lane;
            const int c = (me < end) ? col[me] : NN;  // sentinel row NN is all-zero
            int nb = end - e;
            if (nb > 64) nb = 64;
            const int it = (nb + 31) >> 5;  // 32 edges per j-step
            for (int j = 0; j < it; ++j) {
                const int b = j * 32 + g;
                const int c0 = __shfl(c, b, 64);
                const int c1 = __shfl(c, b + 8, 64);
                const int c2 = __shfl(c, b + 16, 64);
                const int c3 = __shfl(c, b + 24, 64);
                float4 r0 = *(const float4*)(hin + ((size_t)c0 << 6) + fc);
                float4 r1 = *(const float4*)(hin + ((size_t)c1 << 6) + fc);
                float4 r2 = *(const float4*)(hin + ((size_t)c2 << 6) + fc);
                float4 r3 = *(const float4*)(hin + ((size_t)c3 << 6) + fc);
                const __half2* h0 = (const __half2*)&r0;
                const __half2* h1 = (const __half2*)&r1;
                const __half2* h2 = (const __half2*)&r2;
                const __half2* h3 = (const __half2*)&r3;
#pragma unroll
                for (int q = 0; q < 4; ++q) {
                    const float2 f0 = __half22float2(h0[q]);
                    const float2 f1 = __half22float2(h1[q]);
                    const float2 f2 = __half22float2(h2[q]);
                    const float2 f3 = __half22float2(h3[q]);
                    acc[2 * q] += (f0.x + f1.x) + (f2.x + f3.x);
                    acc[2 * q + 1] += (f0.y + f1.y) + (f2.y + f3.y);
                }
            }
        }
        // reduce the 8 groups (lane bits 3..5)
#pragma unroll
        for (int m = 8; m <= 32; m <<= 1)
#pragma unroll
            for (int q = 0; q < 8; ++q) acc[q] += __shfl_xor(acc[q], m, 64);
        if (g == 0) {  // lanes 0..7 hold full sums for chunks 0..7
            float4 r = *(const float4*)(hin + ((size_t)node << 6) + fc);
            const __half2* hh = (const __half2*)&r;
#pragma unroll
            for (int q = 0; q < 4; ++q) {
                const float2 f = __half22float2(hh[q]);
                acc[2 * q] += f.x;
                acc[2 * q + 1] += f.y;
            }
            const float di = dinv[node];
            const float4* xp = (const float4*)(x0 + ((size_t)node << 6) + fc);
            const float4 xa = xp[0], xb = xp[1];
            float4 oa, ob;
            oa.x = 0.5f * fmaf(di, acc[0], xa.x);
            oa.y = 0.5f * fmaf(di, acc[1], xa.y);
            oa.z = 0.5f * fmaf(di, acc[2], xa.z);
            oa.w = 0.5f * fmaf(di, acc[3], xa.w);
            ob.x = 0.5f * fmaf(di, acc[4], xb.x);
            ob.y = 0.5f * fmaf(di, acc[5], xb.y);
            ob.z = 0.5f * fmaf(di, acc[6], xb.z);
            ob.w = 0.5f * fmaf(di, acc[7], xb.w);
            float4* sp = (float4*)(sout + ((size_t)node << 6) + fc);
            sp[0] = oa;
            sp[1] = ob;
        }
    }
}

// ================= MFMA input GEMM =================
// R12/R4: MfmaUtil 1.4%, VALUBusy 9% -> ALU work gone; the ~80us is a
// staging/latency floor (~1.2TB/s aggregate read). Bytes are the only lever
// left here; keep as-is.

__global__ __launch_bounds__(256, 4) void mgemm_in_v1(
    const float* __restrict__ A, const __half* __restrict__ wt,
    const float* __restrict__ bias, const float* __restrict__ dinvp,
    float* __restrict__ out32, __half* __restrict__ out16) {
    __shared__ __half sh[64][264];
    const int t = threadIdx.x;
    const int row0 = blockIdx.x * 64;

    // stage x tile (64 rows x 256 k) as fp16
#pragma unroll
    for (int i = 0; i < 16; ++i) {
        const int linear = t + i * 256;  // 0..4095, 64 float4 per row
        const int r = linear >> 6;
        const int q = linear & 63;
        const int grow = row0 + r;
        float4 v = make_float4(0.f, 0.f, 0.f, 0.f);
        if (grow < NN) v = *(const float4*)&A[(size_t)grow * 256 + q * 4];
        __half2* dst = (__half2*)&sh[r][q * 4];
        dst[0] = __floats2half2_rn(v.x, v.y);
        dst[1] = __floats2half2_rn(v.z, v.w);
    }
    __syncthreads();

    const int lane = t & 63;
    const int w = t >> 6;  // wave 0..3 -> rows [w*16, w*16+16)
    const int la = lane & 15, lg = lane >> 4;
    f32x4 acc[4] = {};
    const __half* arow = &sh[w * 16 + la][0];
#pragma unroll
    for (int kc = 0; kc < 8; ++kc) {
        const int k0 = kc * 32 + lg * 8;
        const f16x8 a = *(const f16x8*)&arow[k0];
#pragma unroll
        for (int tt = 0; tt < 4; ++tt) {
            const f16x8 b = *(const f16x8*)&wt[(size_t)(la + 16 * tt) * 256 + k0];
            acc[tt] = __builtin_amdgcn_mfma_f32_16x16x32_f16(a, b, acc[tt], 0, 0, 0);
        }
    }

    // epilogue: o = elu(acc + bias); out32 = o; out16 = half(o * dinv)
#pragma unroll
    for (int i = 0; i < 4; ++i) {
        const int r = row0 + w * 16 + lg * 4 + i;
        if (r >= NN) continue;
        const float dv = dinvp[r];
#pragma unroll
        for (int tt = 0; tt < 4; ++tt) {
            const int c = la + 16 * tt;
            float o = acc[tt][i] + bias[c];
            o = eluf(o);
            out32[(size_t)r * 64 + c] = o;
            out16[(size_t)r * 64 + c] = __float2half(o * dv);
        }
    }
}

// ================= layer GEMM v5: MFMA with exact fp32 identity =================
// R13 theory: o = s@(bW+(1-b)I) = b*(s@W) + (1-b)*s. MFMA only the b*(s@W)
// term (A = s cvt'd fp16 in-reg, B = precomputed (b*W)^T fp16 table, layouts
// identical to hw-verified mgemm_in_v1); add (1-b)*s EXACTLY in fp32 from the
// LDS tile. Kills the dominant (1-b)*ds fp16-identity error that would
// compound over 8 layers; only the b-weighted mixed term is fp16.
// LDS 33.8KB -> 17.4KB => 8 blocks/CU; VALU/thread ~5x less.

__global__ __launch_bounds__(256, 8) void lgemm_v5(
    const float* __restrict__ S, const __half* __restrict__ wt, float obeta,
    const float* __restrict__ dinvp, __half* __restrict__ out16,
    float* __restrict__ out32, int w32) {
    __shared__ float sa[64][68];
    const int t = threadIdx.x;
    const int row0 = blockIdx.x * 64;

    // stage s tile 64x64 fp32 (4 float4 per thread)
#pragma unroll
    for (int i = 0; i < 4; ++i) {
        const int linear = t + i * 256;
        const int r = linear >> 4, q = linear & 15;
        const int grow = row0 + r;
        float4 v = make_float4(0.f, 0.f, 0.f, 0.f);
        if (grow < NN) v = *(const float4*)&S[(size_t)grow * 64 + q * 4];
        *(float4*)&sa[r][q * 4] = v;
    }
    __syncthreads();

    const int lane = t & 63;
    const int w = t >> 6;
    const int la = lane & 15, lg = lane >> 4;
    f32x4 acc[4] = {};
    const float* arow = &sa[w * 16 + la][0];
#pragma unroll
    for (int kc = 0; kc < 2; ++kc) {
        const int k0 = kc * 32 + lg * 8;
        const float4 s0 = *(const float4*)&arow[k0];
        const float4 s1 = *(const float4*)&arow[k0 + 4];
        f16x8 a;
        a[0] = (_Float16)s0.x; a[1] = (_Float16)s0.y;
        a[2] = (_Float16)s0.z; a[3] = (_Float16)s0.w;
        a[4] = (_Float16)s1.x; a[5] = (_Float16)s1.y;
        a[6] = (_Float16)s1.z; a[7] = (_Float16)s1.w;
#pragma unroll
        for (int tt = 0; tt < 4; ++tt) {
            const f16x8 b = *(const f16x8*)&wt[(size_t)(la + 16 * tt) * 64 + k0];
            acc[tt] = __builtin_amdgcn_mfma_f32_16x16x32_f16(a, b, acc[tt], 0, 0, 0);
        }
    }

    // epilogue: o = acc + (1-beta)*s (exact fp32 identity); h = elu(o)+o
#pragma unroll
    for (int i = 0; i < 4; ++i) {
        const int lr = w * 16 + lg * 4 + i;
        const int r = row0 + lr;
        if (r >= NN) continue;
        const float dv = dinvp[r];
#pragma unroll
        for (int tt = 0; tt < 4; ++tt) {
            const int c = la + 16 * tt;
            const float o = acc[tt][i] + obeta * sa[lr][c];
            const float h = eluf(o) + o;
            out16[(size_t)r * 64 + c] = __float2half(h * dv);
            if (w32) out32[(size_t)r * 64 + c] = h;
        }
    }
}

// ================= dense GEMM for output layer (R2-proven shape) =================
// MODE 2: out32 = A@B + bias    (KTOT=64)

template <int KTOT, int MODE>
__global__ __launch_bounds__(256, 4) void gemm_v2(const float* __restrict__ A,
                                                  const float* __restrict__ B,
                                                  const float* __restrict__ bias,
                                                  const float* __restrict__ dinvp,
                                                  float* __restrict__ out32,
                                                  __half* __restrict__ out16) {
    __shared__ float ss[64][68];
    __shared__ float ws[64][64];
    const int t = threadIdx.x;
    const int row0 = blockIdx.x * 64;
    const int tx = t & 15, ty = t >> 4;
    float acc[4][4] = {};

    for (int kc = 0; kc < KTOT; kc += 64) {
#pragma unroll
        for (int i = 0; i < 4; ++i) {
            const int linear = t + i * 256;
            const int r = linear >> 4, q = linear & 15;
            const int grow = row0 + r;
            float4 v = make_float4(0.f, 0.f, 0.f, 0.f);
            if (grow < NN) v = *(const float4*)&A[(size_t)grow * KTOT + kc + q * 4];
            *(float4*)&ss[r][q * 4] = v;
        }
#pragma unroll
        for (int i = 0; i < 4; ++i) {
            const int linear = t + i * 256;
            const int r = linear >> 4, q = linear & 15;
            *(float4*)&ws[r][q * 4] = *(const float4*)&B[(size_t)(kc + r) * 64 + q * 4];
        }
        __syncthreads();
#pragma unroll 4
        for (int k = 0; k < 64; k += 4) {
            float4 af[4], bf[4];
            af[0] = *(const float4*)&ss[ty * 4 + 0][k];
            af[1] = *(const float4*)&ss[ty * 4 + 1][k];
            af[2] = *(const float4*)&ss[ty * 4 + 2][k];
            af[3] = *(const float4*)&ss[ty * 4 + 3][k];
            bf[0] = *(const float4*)&ws[k + 0][tx * 4];
            bf[1] = *(const float4*)&ws[k + 1][tx * 4];
            bf[2] = *(const float4*)&ws[k + 2][tx * 4];
            bf[3] = *(const float4*)&ws[k + 3][tx * 4];
            const float* A4 = (const float*)af;
            const float* B4 = (const float*)bf;
#pragma unroll
            for (int i = 0; i < 4; ++i)
#pragma unroll
                for (int kk = 0; kk < 4; ++kk)
#pragma unroll
                    for (int j = 0; j < 4; ++j)
                        acc[i][j] = fmaf(A4[i * 4 + kk], B4[kk * 4 + j], acc[i][j]);
        }
        __syncthreads();
    }

#pragma unroll
    for (int i = 0; i < 4; ++i) {
        const int r = row0 + ty * 4 + i;
        if (r >= NN) continue;
        float4 o;
        float* op = (float*)&o;
#pragma unroll
        for (int j = 0; j < 4; ++j) {
            float xv = acc[i][j] + bias[tx * 4 + j];
            if (MODE == 0) xv = eluf(xv);
            op[j] = xv;
        }
        *(float4*)&out32[(size_t)r * 64 + tx * 4] = o;
        if (MODE == 0) {
            const float dv = dinvp[r];
            __half2* hp = (__half2*)&out16[(size_t)r * 64 + tx * 4];
            hp[0] = __floats2half2_rn(o.x * dv, o.y * dv);
            hp[1] = __floats2half2_rn(o.z * dv, o.w * dv);
        }
    }
}

// ================= launch =================

extern "C" void kernel_launch(void* const* d_in, const int* in_sizes, int n_in, void* d_out,
                              int out_size, void* d_ws, size_t ws_size, hipStream_t stream) {
    const float* x = (const float*)d_in[0];
    const int* ei = (const int*)d_in[1];
    const float* w_in = (const float*)d_in[2];
    const float* b_in = (const float*)d_in[3];
    const float* w_layers = (const float*)d_in[4];
    const float* w_out = (const float*)d_in[5];
    const float* b_out = (const float*)d_in[6];
    float* out = (float*)d_out;

    char* p = (char*)d_ws;
    auto alloc = [&](size_t bytes) -> char* {
        char* r = p;
        p += (bytes + 255) & ~(size_t)255;
        return r;
    };
    int* counts = (int*)alloc((size_t)NN * 4);
    int* bfill = (int*)alloc((size_t)NBUCK * 4);
    int* rp = (int*)alloc((size_t)(NN + 1) * 4);
    int* partial = (int*)alloc(128 * 4);
    float* dinv = (float*)alloc((size_t)NN * 4);
    int* colA = (int*)alloc((size_t)EE * 4);
    unsigned* tmp = (unsigned*)alloc((size_t)EE * 4);         // binned packed edges
    float* x0 = (float*)alloc((size_t)NN * HH * 4);           // fp32 residual
    __half* x0h = (__half*)alloc((size_t)(NN + 1) * HH * 2);  // scaled gather buf A
    __half* hA = (__half*)alloc((size_t)(NN + 1) * HH * 2);   // scaled gather buf B
    float* sbuf = (float*)alloc((size_t)NN * HH * 4);         // fp32 s / final fp32 h
    __half* wt = (__half*)alloc((size_t)64 * 256 * 2);        // w_in^T fp16
    __half* btab = (__half*)alloc((size_t)LL * 64 * 64 * 2);  // per-layer (beta*W)^T fp16

    const int* srcA = ei;
    const int* dstA = ei + EE;

    hipMemsetAsync(counts, 0, (size_t)NN * 4, stream);
    hipMemsetAsync(bfill, 0, (size_t)NBUCK * 4, stream);
    init_sent_v2<<<1, 128, 0, stream>>>(x0h, hA);
    conv_w_v1<<<1, 256, 0, stream>>>(w_in, wt);
    conv_wbl_v1<<<LL, 256, 0, stream>>>(w_layers, btab);
    count_edges_v2<<<(EE + 255) / 256, 256, 0, stream>>>(dstA, counts);
    scan_block_v2<<<NBLK, 256, 0, stream>>>(counts, rp, partial, dinv);
    scan_top_v2<<<1, 128, 0, stream>>>(partial);
    scan_add_v2<<<(NN + 1 + 255) / 256, 256, 0, stream>>>(rp, partial);
    bin_edges_v1<<<(EE + BIN_CHUNK - 1) / BIN_CHUNK, 256, 0, stream>>>(srcA, dstA, rp, bfill,
                                                                       tmp);
    unbin_v1<<<NBUCK, 512, 0, stream>>>(tmp, rp, colA);

    // x0 = elu(x @ w_in + b_in);  x0h = half(dinv * x0)   [MFMA]
    mgemm_in_v1<<<(NN + 63) / 64, 256, 0, stream>>>(x, wt, b_in, dinv, x0, x0h);

    for (int l = 0; l < LL; ++l) {
        const float beta = (float)log(1.0 / (double)(l + 1) + 1.0);
        const float obeta = 1.0f - beta;
        const __half* hin = (l & 1) ? hA : x0h;  // l=0 reads x0h
        __half* hout = (l & 1) ? x0h : hA;
        agg_v2<<<AGG_BLOCKS, 256, 0, stream>>>(rp, colA, dinv, hin, x0, sbuf);
        lgemm_v5<<<(NN + 63) / 64, 256, 0, stream>>>(sbuf, btab + (size_t)l * 64 * 64, obeta,
                                                     dinv, hout, sbuf, l == LL - 1);
    }
    gemm_v2<64, 2><<<(NN + 63) / 64, 256, 0, stream>>>(sbuf, w_out, b_out, nullptr, out, nullptr);
}

// Round 6
// 765.164 us; speedup vs baseline: 1.2126x; 1.1110x over previous
//
#include <hip/hip_runtime.h>
#include <hip/hip_fp16.h>
#include <math.h>

#define NN 100000
#define EE 1600000
#define HH 64
#define LL 8
#define NBLK ((NN + 1023) / 1024)
#define AGG3_BLOCKS ((NN + 31) / 32)  // 4 waves x 8 nodes per block

// binned scatter params
#define NPB 512                         // nodes per bucket (pow2)
#define BSH 9                           // log2(NPB)
#define NBUCK ((NN + NPB - 1) / NPB)    // 196
#define BIN_CHUNK 4096                  // edges per bin block (16/thread)

typedef _Float16 f16x8 __attribute__((ext_vector_type(8)));
typedef float f32x4 __attribute__((ext_vector_type(4)));

__device__ __forceinline__ float eluf(float x) { return x > 0.0f ? x : expm1f(x); }

// ================= CSR build =================

__global__ void count_edges_v2(const int* __restrict__ dst, int* __restrict__ counts) {
    int i = blockIdx.x * blockDim.x + threadIdx.x;
    if (i < EE) atomicAdd(&counts[dst[i]], 1);
}

__global__ void scan_block_v2(const int* __restrict__ counts, int* __restrict__ rp,
                              int* __restrict__ partial, float* __restrict__ dinv) {
    __shared__ int sm[256];
    const int t = threadIdx.x;
    const int base = blockIdx.x * 1024 + t * 4;
    int v0 = 0, v1 = 0, v2 = 0, v3 = 0;
    if (base + 0 < NN) v0 = counts[base + 0];
    if (base + 1 < NN) v1 = counts[base + 1];
    if (base + 2 < NN) v2 = counts[base + 2];
    if (base + 3 < NN) v3 = counts[base + 3];
    if (base + 0 < NN) dinv[base + 0] = rsqrtf((float)(v0 + 1));
    if (base + 1 < NN) dinv[base + 1] = rsqrtf((float)(v1 + 1));
    if (base + 2 < NN) dinv[base + 2] = rsqrtf((float)(v2 + 1));
    if (base + 3 < NN) dinv[base + 3] = rsqrtf((float)(v3 + 1));
    const int s = v0 + v1 + v2 + v3;
    sm[t] = s;
    __syncthreads();
    for (int off = 1; off < 256; off <<= 1) {
        int x = 0;
        if (t >= off) x = sm[t - off];
        __syncthreads();
        if (t >= off) sm[t] += x;
        __syncthreads();
    }
    int excl = sm[t] - s;
    if (t == 255) partial[blockIdx.x] = sm[255];
    if (base + 0 < NN) rp[base + 0] = excl;
    excl += v0;
    if (base + 1 < NN) rp[base + 1] = excl;
    excl += v1;
    if (base + 2 < NN) rp[base + 2] = excl;
    excl += v2;
    if (base + 3 < NN) rp[base + 3] = excl;
}

__global__ void scan_top_v2(int* partial) {
    __shared__ int sm[128];
    const int t = threadIdx.x;
    const int v = (t < NBLK) ? partial[t] : 0;
    sm[t] = v;
    __syncthreads();
    for (int off = 1; off < 128; off <<= 1) {
        int x = 0;
        if (t >= off) x = sm[t - off];
        __syncthreads();
        if (t >= off) sm[t] += x;
        __syncthreads();
    }
    if (t < NBLK) partial[t] = sm[t] - v;  // exclusive
}

__global__ void scan_add_v2(int* rp, const int* __restrict__ partial) {
    const int i = blockIdx.x * blockDim.x + threadIdx.x;
    if (i < NN) rp[i] += partial[i >> 10];
    else if (i == NN) rp[NN] = EE;
}

// ================= binned scatter =================
// R10: scatter_v2 wrote 107MB HBM for a 6.4MB payload. Two-phase binning
// keeps writes in hot windows. Measured R2: saved ~45us net.

__global__ __launch_bounds__(256) void bin_edges_v1(const int* __restrict__ src,
                                                    const int* __restrict__ dst,
                                                    const int* __restrict__ rp,
                                                    int* __restrict__ bfill,
                                                    unsigned* __restrict__ tmp) {
    __shared__ int hist[NBUCK];
    __shared__ int basei[NBUCK];
    __shared__ int rpb[NBUCK];
    __shared__ int cur[NBUCK];
    const int t = threadIdx.x;
    const int e0 = blockIdx.x * BIN_CHUNK;
    for (int b = t; b < NBUCK; b += 256) {
        hist[b] = 0;
        cur[b] = 0;
    }
    __syncthreads();
    int myd[16];
#pragma unroll
    for (int i = 0; i < 16; ++i) {
        const int e = e0 + i * 256 + t;
        int d = -1;
        if (e < EE) {
            d = dst[e];
            atomicAdd(&hist[d >> BSH], 1);
        }
        myd[i] = d;
    }
    __syncthreads();
    for (int b = t; b < NBUCK; b += 256) {
        const int h = hist[b];
        basei[b] = h ? atomicAdd(&bfill[b], h) : 0;
        rpb[b] = rp[b << BSH];
    }
    __syncthreads();
#pragma unroll
    for (int i = 0; i < 16; ++i) {
        const int e = e0 + i * 256 + t;
        if (e < EE) {
            const int d = myd[i];
            const int b = d >> BSH;
            const int slot = atomicAdd(&cur[b], 1);
            tmp[rpb[b] + basei[b] + slot] =
                ((unsigned)(d & (NPB - 1)) << 17) | (unsigned)src[e];
        }
    }
}

__global__ __launch_bounds__(512) void unbin_v1(const unsigned* __restrict__ tmp,
                                                const int* __restrict__ rp,
                                                int* __restrict__ col) {
    __shared__ int lrp[NPB];
    __shared__ int lfill[NPB];
    const int t = threadIdx.x;
    const int node0 = blockIdx.x << BSH;
    const int nodes = (NN - node0 < NPB) ? (NN - node0) : NPB;
    for (int i = t; i < nodes; i += 512) {
        lrp[i] = rp[node0 + i];
        lfill[i] = 0;
    }
    __syncthreads();
    const int lo = rp[node0];
    const int hi = rp[node0 + nodes];
    for (int e = lo + t; e < hi; e += 512) {
        const unsigned v = tmp[e];
        const int s = (int)(v & 0x1FFFFu);
        const int doff = (int)(v >> 17);
        const int pos = lrp[doff] + atomicAdd(&lfill[doff], 1);
        col[pos] = s;
    }
}

// zero sentinel row NN of both fp16 gather buffers (masked lanes gather row NN)
__global__ void init_sent_v2(__half* a, __half* b) {
    const int t = threadIdx.x;
    if (t < 64) a[(size_t)NN * HH + t] = __float2half(0.f);
    else b[(size_t)NN * HH + (t - 64)] = __float2half(0.f);
}

// w_in [256][64] fp32 -> wt [64][256] fp16 (transposed, for MFMA B-fragments)
__global__ void conv_w_v1(const float* __restrict__ w, __half* __restrict__ wt) {
    const int t = threadIdx.x;  // 256
    const int c = t & 63;
    const int k0 = (t >> 6) * 64;
    for (int k = 0; k < 64; ++k)
        wt[(size_t)c * 256 + k0 + k] = __float2half(w[(size_t)(k0 + k) * 64 + c]);
}

// per-layer (beta_l * W_l)^T as fp16: btab[l][c][k] = beta_l * W_l[k][c]
// NOTE: identity term is NOT folded in (added exactly in fp32 in lgemm_v5 epilogue).
__global__ void conv_wbl_v1(const float* __restrict__ w_layers, __half* __restrict__ btab) {
    const int l = blockIdx.x;
    const float beta = logf(1.0f / (float)(l + 1) + 1.0f);
    const float* W = w_layers + (size_t)l * 64 * 64;
    __half* wt = btab + (size_t)l * 64 * 64;
    const int t = threadIdx.x;     // 256
    const int c = t & 63;          // output col
    const int k0 = (t >> 6) * 16;  // 16 k each
    for (int k = k0; k < k0 + 16; ++k)
        wt[(size_t)c * 64 + k] = __float2half(beta * W[(size_t)k * 64 + c]);
}

// ================= aggregation v3: 8 nodes/wave, group-owned, no reduce =================
// R14 theory: agg_v2 spent ~47% of edge-slots on sentinels (Poisson-16 degree vs
// 32-slot j-steps) plus a 24-shfl x 3-round cross-group reduce per node. v3: one
// 8-lane group owns ALL 64 features of one node (lane = 8-feature chunk), walks
// its edge list 4 edges at a time. Same MLP (32 random rows in flight/wave), same
// coalescing (8 random 128B rows per vmem), zero reduce, zero slot waste.
// Cost: intra-wave max-degree divergence (~1.5x on Poisson max-of-8).
// DIAGNOSTIC: if flat vs agg_v2, agg is at the random-gather BW roofline.

__global__ __launch_bounds__(256) void agg_v3(
    const int* __restrict__ rp, const int* __restrict__ col, const float* __restrict__ dinv,
    const __half* __restrict__ hin, const float* __restrict__ x0, float* __restrict__ sout) {
    const int lane = threadIdx.x & 63;
    const int g = lane >> 3;         // group 0..7 -> node
    const int fc = (lane & 7) << 3;  // feature chunk base
    const int wid = blockIdx.x * 4 + (threadIdx.x >> 6);
    const int node = wid * 8 + g;
    if (node >= NN) return;

    const int start = rp[node], end = rp[node + 1];
    float acc[8] = {};
    for (int e = start; e < end; e += 4) {
        const int c0 = col[e];
        const int c1 = (e + 1 < end) ? col[e + 1] : NN;  // sentinel row NN all-zero
        const int c2 = (e + 2 < end) ? col[e + 2] : NN;
        const int c3 = (e + 3 < end) ? col[e + 3] : NN;
        float4 r0 = *(const float4*)(hin + ((size_t)c0 << 6) + fc);
        float4 r1 = *(const float4*)(hin + ((size_t)c1 << 6) + fc);
        float4 r2 = *(const float4*)(hin + ((size_t)c2 << 6) + fc);
        float4 r3 = *(const float4*)(hin + ((size_t)c3 << 6) + fc);
        const __half2* h0 = (const __half2*)&r0;
        const __half2* h1 = (const __half2*)&r1;
        const __half2* h2 = (const __half2*)&r2;
        const __half2* h3 = (const __half2*)&r3;
#pragma unroll
        for (int q = 0; q < 4; ++q) {
            const float2 f0 = __half22float2(h0[q]);
            const float2 f1 = __half22float2(h1[q]);
            const float2 f2 = __half22float2(h2[q]);
            const float2 f3 = __half22float2(h3[q]);
            acc[2 * q] += (f0.x + f1.x) + (f2.x + f3.x);
            acc[2 * q + 1] += (f0.y + f1.y) + (f2.y + f3.y);
        }
    }
    // self row + residual + write (every lane owns its 8-feature chunk)
    {
        float4 r = *(const float4*)(hin + ((size_t)node << 6) + fc);
        const __half2* hh = (const __half2*)&r;
#pragma unroll
        for (int q = 0; q < 4; ++q) {
            const float2 f = __half22float2(hh[q]);
            acc[2 * q] += f.x;
            acc[2 * q + 1] += f.y;
        }
        const float di = dinv[node];
        const float4* xp = (const float4*)(x0 + ((size_t)node << 6) + fc);
        const float4 xa = xp[0], xb = xp[1];
        float4 oa, ob;
        oa.x = 0.5f * fmaf(di, acc[0], xa.x);
        oa.y = 0.5f * fmaf(di, acc[1], xa.y);
        oa.z = 0.5f * fmaf(di, acc[2], xa.z);
        oa.w = 0.5f * fmaf(di, acc[3], xa.w);
        ob.x = 0.5f * fmaf(di, acc[4], xb.x);
        ob.y = 0.5f * fmaf(di, acc[5], xb.y);
        ob.z = 0.5f * fmaf(di, acc[6], xb.z);
        ob.w = 0.5f * fmaf(di, acc[7], xb.w);
        float4* sp = (float4*)(sout + ((size_t)node << 6) + fc);
        sp[0] = oa;
        sp[1] = ob;
    }
}

// ================= MFMA input GEMM v2: half LDS, higher occupancy =================
// R4: MfmaUtil 1.4%, VALUBusy 9%, 1.8TB/s aggregate at occupancy 32% (LDS-capped
// 4 blk/CU) -> latency-bound streaming. v2: stage k in 2x128 chunks ([64][136]
// fp16 = 17.4KB, 16B-aligned rows, 2-way bank alias = free) + launch_bounds(256,6)
// -> 6 blk/CU, +50% resident waves. Same bytes.

__global__ __launch_bounds__(256, 6) void mgemm_in_v2(
    const float* __restrict__ A, const __half* __restrict__ wt,
    const float* __restrict__ bias, const float* __restrict__ dinvp,
    float* __restrict__ out32, __half* __restrict__ out16) {
    __shared__ __half sh[64][136];
    const int t = threadIdx.x;
    const int row0 = blockIdx.x * 64;
    const int lane = t & 63;
    const int w = t >> 6;  // wave 0..3 -> rows [w*16, w*16+16)
    const int la = lane & 15, lg = lane >> 4;
    f32x4 acc[4] = {};

#pragma unroll
    for (int kh = 0; kh < 2; ++kh) {
        // stage 64 rows x 128 k as fp16 (8 float4-src loads per thread)
#pragma unroll
        for (int i = 0; i < 8; ++i) {
            const int linear = t + i * 256;  // 0..2047, 32 float4 per row
            const int r = linear >> 5;
            const int q = linear & 31;
            const int grow = row0 + r;
            float4 v = make_float4(0.f, 0.f, 0.f, 0.f);
            if (grow < NN) v = *(const float4*)&A[(size_t)grow * 256 + kh * 128 + q * 4];
            __half2* dst = (__half2*)&sh[r][q * 4];
            dst[0] = __floats2half2_rn(v.x, v.y);
            dst[1] = __floats2half2_rn(v.z, v.w);
        }
        __syncthreads();
        const __half* arow = &sh[w * 16 + la][0];
#pragma unroll
        for (int kc = 0; kc < 4; ++kc) {
            const int k0 = kc * 32 + lg * 8;
            const f16x8 a = *(const f16x8*)&arow[k0];
#pragma unroll
            for (int tt = 0; tt < 4; ++tt) {
                const f16x8 b = *(const f16x8*)&wt[(size_t)(la + 16 * tt) * 256 + kh * 128 + k0];
                acc[tt] = __builtin_amdgcn_mfma_f32_16x16x32_f16(a, b, acc[tt], 0, 0, 0);
            }
        }
        __syncthreads();
    }

    // epilogue: o = elu(acc + bias); out32 = o; out16 = half(o * dinv)
#pragma unroll
    for (int i = 0; i < 4; ++i) {
        const int r = row0 + w * 16 + lg * 4 + i;
        if (r >= NN) continue;
        const float dv = dinvp[r];
#pragma unroll
        for (int tt = 0; tt < 4; ++tt) {
            const int c = la + 16 * tt;
            float o = acc[tt][i] + bias[c];
            o = eluf(o);
            out32[(size_t)r * 64 + c] = o;
            out16[(size_t)r * 64 + c] = __float2half(o * dv);
        }
    }
}

// ================= layer GEMM v5: MFMA with exact fp32 identity =================
// R13 (verified R5: -30us, absmax unchanged): o = b*(s@W) + (1-b)*s. MFMA the
// b-term (B = (b*W)^T fp16 table); identity added exactly in fp32 from LDS.

__global__ __launch_bounds__(256, 8) void lgemm_v5(
    const float* __restrict__ S, const __half* __restrict__ wt, float obeta,
    const float* __restrict__ dinvp, __half* __restrict__ out16,
    float* __restrict__ out32, int w32) {
    __shared__ float sa[64][68];
    const int t = threadIdx.x;
    const int row0 = blockIdx.x * 64;

    // stage s tile 64x64 fp32 (4 float4 per thread)
#pragma unroll
    for (int i = 0; i < 4; ++i) {
        const int linear = t + i * 256;
        const int r = linear >> 4, q = linear & 15;
        const int grow = row0 + r;
        float4 v = make_float4(0.f, 0.f, 0.f, 0.f);
        if (grow < NN) v = *(const float4*)&S[(size_t)grow * 64 + q * 4];
        *(float4*)&sa[r][q * 4] = v;
    }
    __syncthreads();

    const int lane = t & 63;
    const int w = t >> 6;
    const int la = lane & 15, lg = lane >> 4;
    f32x4 acc[4] = {};
    const float* arow = &sa[w * 16 + la][0];
#pragma unroll
    for (int kc = 0; kc < 2; ++kc) {
        const int k0 = kc * 32 + lg * 8;
        const float4 s0 = *(const float4*)&arow[k0];
        const float4 s1 = *(const float4*)&arow[k0 + 4];
        f16x8 a;
        a[0] = (_Float16)s0.x; a[1] = (_Float16)s0.y;
        a[2] = (_Float16)s0.z; a[3] = (_Float16)s0.w;
        a[4] = (_Float16)s1.x; a[5] = (_Float16)s1.y;
        a[6] = (_Float16)s1.z; a[7] = (_Float16)s1.w;
#pragma unroll
        for (int tt = 0; tt < 4; ++tt) {
            const f16x8 b = *(const f16x8*)&wt[(size_t)(la + 16 * tt) * 64 + k0];
            acc[tt] = __builtin_amdgcn_mfma_f32_16x16x32_f16(a, b, acc[tt], 0, 0, 0);
        }
    }

    // epilogue: o = acc + (1-beta)*s (exact fp32 identity); h = elu(o)+o
#pragma unroll
    for (int i = 0; i < 4; ++i) {
        const int lr = w * 16 + lg * 4 + i;
        const int r = row0 + lr;
        if (r >= NN) continue;
        const float dv = dinvp[r];
#pragma unroll
        for (int tt = 0; tt < 4; ++tt) {
            const int c = la + 16 * tt;
            const float o = acc[tt][i] + obeta * sa[lr][c];
            const float h = eluf(o) + o;
            out16[(size_t)r * 64 + c] = __float2half(h * dv);
            if (w32) out32[(size_t)r * 64 + c] = h;
        }
    }
}

// ================= dense GEMM for output layer (R2-proven shape) =================
// MODE 2: out32 = A@B + bias    (KTOT=64)

template <int KTOT, int MODE>
__global__ __launch_bounds__(256, 4) void gemm_v2(const float* __restrict__ A,
                                                  const float* __restrict__ B,
                                                  const float* __restrict__ bias,
                                                  const float* __restrict__ dinvp,
                                                  float* __restrict__ out32,
                                                  __half* __restrict__ out16) {
    __shared__ float ss[64][68];
    __shared__ float ws[64][64];
    const int t = threadIdx.x;
    const int row0 = blockIdx.x * 64;
    const int tx = t & 15, ty = t >> 4;
    float acc[4][4] = {};

    for (int kc = 0; kc < KTOT; kc += 64) {
#pragma unroll
        for (int i = 0; i < 4; ++i) {
            const int linear = t + i * 256;
            const int r = linear >> 4, q = linear & 15;
            const int grow = row0 + r;
            float4 v = make_float4(0.f, 0.f, 0.f, 0.f);
            if (grow < NN) v = *(const float4*)&A[(size_t)grow * KTOT + kc + q * 4];
            *(float4*)&ss[r][q * 4] = v;
        }
#pragma unroll
        for (int i = 0; i < 4; ++i) {
            const int linear = t + i * 256;
            const int r = linear >> 4, q = linear & 15;
            *(float4*)&ws[r][q * 4] = *(const float4*)&B[(size_t)(kc + r) * 64 + q * 4];
        }
        __syncthreads();
#pragma unroll 4
        for (int k = 0; k < 64; k += 4) {
            float4 af[4], bf[4];
            af[0] = *(const float4*)&ss[ty * 4 + 0][k];
            af[1] = *(const float4*)&ss[ty * 4 + 1][k];
            af[2] = *(const float4*)&ss[ty * 4 + 2][k];
            af[3] = *(const float4*)&ss[ty * 4 + 3][k];
            bf[0] = *(const float4*)&ws[k + 0][tx * 4];
            bf[1] = *(const float4*)&ws[k + 1][tx * 4];
            bf[2] = *(const float4*)&ws[k + 2][tx * 4];
            bf[3] = *(const float4*)&ws[k + 3][tx * 4];
            const float* A4 = (const float*)af;
            const float* B4 = (const float*)bf;
#pragma unroll
            for (int i = 0; i < 4; ++i)
#pragma unroll
                for (int kk = 0; kk < 4; ++kk)
#pragma unroll
                    for (int j = 0; j < 4; ++j)
                        acc[i][j] = fmaf(A4[i * 4 + kk], B4[kk * 4 + j], acc[i][j]);
        }
        __syncthreads();
    }

#pragma unroll
    for (int i = 0; i < 4; ++i) {
        const int r = row0 + ty * 4 + i;
        if (r >= NN) continue;
        float4 o;
        float* op = (float*)&o;
#pragma unroll
        for (int j = 0; j < 4; ++j) {
            float xv = acc[i][j] + bias[tx * 4 + j];
            if (MODE == 0) xv = eluf(xv);
            op[j] = xv;
        }
        *(float4*)&out32[(size_t)r * 64 + tx * 4] = o;
        if (MODE == 0) {
            const float dv = dinvp[r];
            __half2* hp = (__half2*)&out16[(size_t)r * 64 + tx * 4];
            hp[0] = __floats2half2_rn(o.x * dv, o.y * dv);
            hp[1] = __floats2half2_rn(o.z * dv, o.w * dv);
        }
    }
}

// ================= launch =================

extern "C" void kernel_launch(void* const* d_in, const int* in_sizes, int n_in, void* d_out,
                              int out_size, void* d_ws, size_t ws_size, hipStream_t stream) {
    const float* x = (const float*)d_in[0];
    const int* ei = (const int*)d_in[1];
    const float* w_in = (const float*)d_in[2];
    const float* b_in = (const float*)d_in[3];
    const float* w_layers = (const float*)d_in[4];
    const float* w_out = (const float*)d_in[5];
    const float* b_out = (const float*)d_in[6];
    float* out = (float*)d_out;

    char* p = (char*)d_ws;
    auto alloc = [&](size_t bytes) -> char* {
        char* r = p;
        p += (bytes + 255) & ~(size_t)255;
        return r;
    };
    int* counts = (int*)alloc((size_t)NN * 4);
    int* bfill = (int*)alloc((size_t)NBUCK * 4);
    int* rp = (int*)alloc((size_t)(NN + 1) * 4);
    int* partial = (int*)alloc(128 * 4);
    float* dinv = (float*)alloc((size_t)NN * 4);
    int* colA = (int*)alloc((size_t)EE * 4);
    unsigned* tmp = (unsigned*)alloc((size_t)EE * 4);         // binned packed edges
    float* x0 = (float*)alloc((size_t)NN * HH * 4);           // fp32 residual
    __half* x0h = (__half*)alloc((size_t)(NN + 1) * HH * 2);  // scaled gather buf A
    __half* hA = (__half*)alloc((size_t)(NN + 1) * HH * 2);   // scaled gather buf B
    float* sbuf = (float*)alloc((size_t)NN * HH * 4);         // fp32 s / final fp32 h
    __half* wt = (__half*)alloc((size_t)64 * 256 * 2);        // w_in^T fp16
    __half* btab = (__half*)alloc((size_t)LL * 64 * 64 * 2);  // per-layer (beta*W)^T fp16

    const int* srcA = ei;
    const int* dstA = ei + EE;

    hipMemsetAsync(counts, 0, (size_t)NN * 4, stream);
    hipMemsetAsync(bfill, 0, (size_t)NBUCK * 4, stream);
    init_sent_v2<<<1, 128, 0, stream>>>(x0h, hA);
    conv_w_v1<<<1, 256, 0, stream>>>(w_in, wt);
    conv_wbl_v1<<<LL, 256, 0, stream>>>(w_layers, btab);
    count_edges_v2<<<(EE + 255) / 256, 256, 0, stream>>>(dstA, counts);
    scan_block_v2<<<NBLK, 256, 0, stream>>>(counts, rp, partial, dinv);
    scan_top_v2<<<1, 128, 0, stream>>>(partial);
    scan_add_v2<<<(NN + 1 + 255) / 256, 256, 0, stream>>>(rp, partial);
    bin_edges_v1<<<(EE + BIN_CHUNK - 1) / BIN_CHUNK, 256, 0, stream>>>(srcA, dstA, rp, bfill,
                                                                       tmp);
    unbin_v1<<<NBUCK, 512, 0, stream>>>(tmp, rp, colA);

    // x0 = elu(x @ w_in + b_in);  x0h = half(dinv * x0)   [MFMA]
    mgemm_in_v2<<<(NN + 63) / 64, 256, 0, stream>>>(x, wt, b_in, dinv, x0, x0h);

    for (int l = 0; l < LL; ++l) {
        const float obeta = 1.0f - (float)log(1.0 / (double)(l + 1) + 1.0);
        const __half* hin = (l & 1) ? hA : x0h;  // l=0 reads x0h
        __half* hout = (l & 1) ? x0h : hA;
        agg_v3<<<AGG3_BLOCKS, 256, 0, stream>>>(rp, colA, dinv, hin, x0, sbuf);
        lgemm_v5<<<(NN + 63) / 64, 256, 0, stream>>>(sbuf, btab + (size_t)l * 64 * 64, obeta,
                                                     dinv, hout, sbuf, l == LL - 1);
    }
    gemm_v2<64, 2><<<(NN + 63) / 64, 256, 0, stream>>>(sbuf, w_out, b_out, nullptr, out, nullptr);
}

// Round 7
// 689.752 us; speedup vs baseline: 1.3452x; 1.1093x over previous
//
#include <hip/hip_runtime.h>
#include <hip/hip_fp16.h>
#include <math.h>

#define NN 100000
#define EE 1600000
#define HH 64
#define LL 8
#define NBLK ((NN + 1023) / 1024)

// binned scatter params
#define NPB 512                         // nodes per bucket (pow2)
#define BSH 9                           // log2(NPB)
#define NBUCK ((NN + NPB - 1) / NPB)    // 196
#define BIN_CHUNK 4096                  // edges per bin block (16/thread)

typedef _Float16 f16x8 __attribute__((ext_vector_type(8)));
typedef float f32x4 __attribute__((ext_vector_type(4)));

__device__ __forceinline__ float eluf(float x) { return x > 0.0f ? x : expm1f(x); }

// ================= CSR build =================

__global__ void count_edges_v2(const int* __restrict__ dst, int* __restrict__ counts) {
    int i = blockIdx.x * blockDim.x + threadIdx.x;
    if (i < EE) atomicAdd(&counts[dst[i]], 1);
}

__global__ void scan_block_v2(const int* __restrict__ counts, int* __restrict__ rp,
                              int* __restrict__ partial, float* __restrict__ dinv) {
    __shared__ int sm[256];
    const int t = threadIdx.x;
    const int base = blockIdx.x * 1024 + t * 4;
    int v0 = 0, v1 = 0, v2 = 0, v3 = 0;
    if (base + 0 < NN) v0 = counts[base + 0];
    if (base + 1 < NN) v1 = counts[base + 1];
    if (base + 2 < NN) v2 = counts[base + 2];
    if (base + 3 < NN) v3 = counts[base + 3];
    if (base + 0 < NN) dinv[base + 0] = rsqrtf((float)(v0 + 1));
    if (base + 1 < NN) dinv[base + 1] = rsqrtf((float)(v1 + 1));
    if (base + 2 < NN) dinv[base + 2] = rsqrtf((float)(v2 + 1));
    if (base + 3 < NN) dinv[base + 3] = rsqrtf((float)(v3 + 1));
    const int s = v0 + v1 + v2 + v3;
    sm[t] = s;
    __syncthreads();
    for (int off = 1; off < 256; off <<= 1) {
        int x = 0;
        if (t >= off) x = sm[t - off];
        __syncthreads();
        if (t >= off) sm[t] += x;
        __syncthreads();
    }
    int excl = sm[t] - s;
    if (t == 255) partial[blockIdx.x] = sm[255];
    if (base + 0 < NN) rp[base + 0] = excl;
    excl += v0;
    if (base + 1 < NN) rp[base + 1] = excl;
    excl += v1;
    if (base + 2 < NN) rp[base + 2] = excl;
    excl += v2;
    if (base + 3 < NN) rp[base + 3] = excl;
}

__global__ void scan_top_v2(int* partial) {
    __shared__ int sm[128];
    const int t = threadIdx.x;
    const int v = (t < NBLK) ? partial[t] : 0;
    sm[t] = v;
    __syncthreads();
    for (int off = 1; off < 128; off <<= 1) {
        int x = 0;
        if (t >= off) x = sm[t - off];
        __syncthreads();
        if (t >= off) sm[t] += x;
        __syncthreads();
    }
    if (t < NBLK) partial[t] = sm[t] - v;  // exclusive
}

__global__ void scan_add_v2(int* rp, const int* __restrict__ partial) {
    const int i = blockIdx.x * blockDim.x + threadIdx.x;
    if (i < NN) rp[i] += partial[i >> 10];
    else if (i == NN) rp[NN] = EE;
}

// ================= binned scatter =================
// R10: scatter_v2 wrote 107MB HBM for a 6.4MB payload. Two-phase binning
// keeps writes in hot windows. Measured R2: saved ~45us net.

__global__ __launch_bounds__(256) void bin_edges_v1(const int* __restrict__ src,
                                                    const int* __restrict__ dst,
                                                    const int* __restrict__ rp,
                                                    int* __restrict__ bfill,
                                                    unsigned* __restrict__ tmp) {
    __shared__ int hist[NBUCK];
    __shared__ int basei[NBUCK];
    __shared__ int rpb[NBUCK];
    __shared__ int cur[NBUCK];
    const int t = threadIdx.x;
    const int e0 = blockIdx.x * BIN_CHUNK;
    for (int b = t; b < NBUCK; b += 256) {
        hist[b] = 0;
        cur[b] = 0;
    }
    __syncthreads();
    int myd[16];
#pragma unroll
    for (int i = 0; i < 16; ++i) {
        const int e = e0 + i * 256 + t;
        int d = -1;
        if (e < EE) {
            d = dst[e];
            atomicAdd(&hist[d >> BSH], 1);
        }
        myd[i] = d;
    }
    __syncthreads();
    for (int b = t; b < NBUCK; b += 256) {
        const int h = hist[b];
        basei[b] = h ? atomicAdd(&bfill[b], h) : 0;
        rpb[b] = rp[b << BSH];
    }
    __syncthreads();
#pragma unroll
    for (int i = 0; i < 16; ++i) {
        const int e = e0 + i * 256 + t;
        if (e < EE) {
            const int d = myd[i];
            const int b = d >> BSH;
            const int slot = atomicAdd(&cur[b], 1);
            tmp[rpb[b] + basei[b] + slot] =
                ((unsigned)(d & (NPB - 1)) << 17) | (unsigned)src[e];
        }
    }
}

__global__ __launch_bounds__(512) void unbin_v1(const unsigned* __restrict__ tmp,
                                                const int* __restrict__ rp,
                                                int* __restrict__ col) {
    __shared__ int lrp[NPB];
    __shared__ int lfill[NPB];
    const int t = threadIdx.x;
    const int node0 = blockIdx.x << BSH;
    const int nodes = (NN - node0 < NPB) ? (NN - node0) : NPB;
    for (int i = t; i < nodes; i += 512) {
        lrp[i] = rp[node0 + i];
        lfill[i] = 0;
    }
    __syncthreads();
    const int lo = rp[node0];
    const int hi = rp[node0 + nodes];
    for (int e = lo + t; e < hi; e += 512) {
        const unsigned v = tmp[e];
        const int s = (int)(v & 0x1FFFFu);
        const int doff = (int)(v >> 17);
        const int pos = lrp[doff] + atomicAdd(&lfill[doff], 1);
        col[pos] = s;
    }
}

// zero sentinel row NN of both fp16 gather buffers (masked lanes gather row NN)
__global__ void init_sent_v2(__half* a, __half* b) {
    const int t = threadIdx.x;
    if (t < 64) a[(size_t)NN * HH + t] = __float2half(0.f);
    else b[(size_t)NN * HH + (t - 64)] = __float2half(0.f);
}

// w_in [256][64] fp32 -> wt [64][256] fp16 (transposed, for MFMA B-fragments)
__global__ void conv_w_v1(const float* __restrict__ w, __half* __restrict__ wt) {
    const int t = threadIdx.x;  // 256
    const int c = t & 63;
    const int k0 = (t >> 6) * 64;
    for (int k = 0; k < 64; ++k)
        wt[(size_t)c * 256 + k0 + k] = __float2half(w[(size_t)(k0 + k) * 64 + c]);
}

// per-layer (beta_l * W_l)^T as fp16: btab[l][c][k] = beta_l * W_l[k][c]
// identity term added exactly in fp32 in the fused epilogue.
__global__ void conv_wbl_v1(const float* __restrict__ w_layers, __half* __restrict__ btab) {
    const int l = blockIdx.x;
    const float beta = logf(1.0f / (float)(l + 1) + 1.0f);
    const float* W = w_layers + (size_t)l * 64 * 64;
    __half* wt = btab + (size_t)l * 64 * 64;
    const int t = threadIdx.x;     // 256
    const int c = t & 63;          // output col
    const int k0 = (t >> 6) * 16;  // 16 k each
    for (int k = k0; k < k0 + 16; ++k)
        wt[(size_t)c * 64 + k] = __float2half(beta * W[(size_t)k * 64 + c]);
}

// ================= fused layer v2: agg (v3-structure) -> LDS -> MFMA -> elu ============
// R15: agg wrote sbuf 25.6MB fp32; lgemm_v5 read it straight back = 51MB/layer
// round-trip. R1's fusion failed on TLP (16 waves/CU) + agg_v2's heavy reduce;
// both causes are gone: sa tile is 17.4KB (no W in LDS -> btab stays global/L2),
// agg_v3 structure has no reduce. launch_bounds(256,6): 85-VGPR cap (live ~60,
// no spill), 6 blk/CU = 24 waves/CU; 6 resident blocks hide per-block degree
// tail. Each wave aggs 16 nodes (2 passes x 8-lane groups) into sa, one
// barrier, then the hw-verified lgemm_v5 MFMA + exact-fp32-identity epilogue.
// WRITE_SIZE jump vs 13MB = spill = revert; >78us/layer = TLP theory wrong.

__global__ __launch_bounds__(256, 6) void fused_layer_v2(
    const int* __restrict__ rp, const int* __restrict__ col, const float* __restrict__ dinv,
    const __half* __restrict__ hin, const float* __restrict__ x0,
    const __half* __restrict__ wt, float obeta,
    __half* __restrict__ out16, float* __restrict__ out32, int w32) {
    __shared__ float sa[64][68];
    const int t = threadIdx.x;
    const int row0 = blockIdx.x * 64;
    const int lane = t & 63;
    const int w = t >> 6;            // wave 0..3
    const int g = lane >> 3;         // group 0..7
    const int fc = (lane & 7) << 3;  // feature chunk base

    // ---- agg phase: wave w covers rows [w*16, w*16+16), 8 nodes per pass ----
#pragma unroll
    for (int pass = 0; pass < 2; ++pass) {
        const int lrow = w * 16 + pass * 8 + g;
        const int node = row0 + lrow;
        float acc[8] = {};
        if (node < NN) {
            const int start = rp[node], end = rp[node + 1];
            for (int e = start; e < end; e += 4) {
                const int c0 = col[e];
                const int c1 = (e + 1 < end) ? col[e + 1] : NN;  // row NN all-zero
                const int c2 = (e + 2 < end) ? col[e + 2] : NN;
                const int c3 = (e + 3 < end) ? col[e + 3] : NN;
                float4 r0 = *(const float4*)(hin + ((size_t)c0 << 6) + fc);
                float4 r1 = *(const float4*)(hin + ((size_t)c1 << 6) + fc);
                float4 r2 = *(const float4*)(hin + ((size_t)c2 << 6) + fc);
                float4 r3 = *(const float4*)(hin + ((size_t)c3 << 6) + fc);
                const __half2* h0 = (const __half2*)&r0;
                const __half2* h1 = (const __half2*)&r1;
                const __half2* h2 = (const __half2*)&r2;
                const __half2* h3 = (const __half2*)&r3;
#pragma unroll
                for (int q = 0; q < 4; ++q) {
                    const float2 f0 = __half22float2(h0[q]);
                    const float2 f1 = __half22float2(h1[q]);
                    const float2 f2 = __half22float2(h2[q]);
                    const float2 f3 = __half22float2(h3[q]);
                    acc[2 * q] += (f0.x + f1.x) + (f2.x + f3.x);
                    acc[2 * q + 1] += (f0.y + f1.y) + (f2.y + f3.y);
                }
            }
            float4 r = *(const float4*)(hin + ((size_t)node << 6) + fc);
            const __half2* hh = (const __half2*)&r;
#pragma unroll
            for (int q = 0; q < 4; ++q) {
                const float2 f = __half22float2(hh[q]);
                acc[2 * q] += f.x;
                acc[2 * q + 1] += f.y;
            }
            const float di = dinv[node];
            const float4* xp = (const float4*)(x0 + ((size_t)node << 6) + fc);
            const float4 xa = xp[0], xb = xp[1];
            float4 oa, ob;
            oa.x = 0.5f * fmaf(di, acc[0], xa.x);
            oa.y = 0.5f * fmaf(di, acc[1], xa.y);
            oa.z = 0.5f * fmaf(di, acc[2], xa.z);
            oa.w = 0.5f * fmaf(di, acc[3], xa.w);
            ob.x = 0.5f * fmaf(di, acc[4], xb.x);
            ob.y = 0.5f * fmaf(di, acc[5], xb.y);
            ob.z = 0.5f * fmaf(di, acc[6], xb.z);
            ob.w = 0.5f * fmaf(di, acc[7], xb.w);
            *(float4*)&sa[lrow][fc] = oa;
            *(float4*)&sa[lrow][fc + 4] = ob;
        } else {
            *(float4*)&sa[lrow][fc] = make_float4(0.f, 0.f, 0.f, 0.f);
            *(float4*)&sa[lrow][fc + 4] = make_float4(0.f, 0.f, 0.f, 0.f);
        }
    }
    __syncthreads();

    // ---- GEMM phase (lgemm_v5 body): o = b*(s@W) + (1-b)*s ----
    const int la = lane & 15, lg = lane >> 4;
    f32x4 acc2[4] = {};
    const float* arow = &sa[w * 16 + la][0];
#pragma unroll
    for (int kc = 0; kc < 2; ++kc) {
        const int k0 = kc * 32 + lg * 8;
        const float4 s0 = *(const float4*)&arow[k0];
        const float4 s1 = *(const float4*)&arow[k0 + 4];
        f16x8 a;
        a[0] = (_Float16)s0.x; a[1] = (_Float16)s0.y;
        a[2] = (_Float16)s0.z; a[3] = (_Float16)s0.w;
        a[4] = (_Float16)s1.x; a[5] = (_Float16)s1.y;
        a[6] = (_Float16)s1.z; a[7] = (_Float16)s1.w;
#pragma unroll
        for (int tt = 0; tt < 4; ++tt) {
            const f16x8 b = *(const f16x8*)&wt[(size_t)(la + 16 * tt) * 64 + k0];
            acc2[tt] = __builtin_amdgcn_mfma_f32_16x16x32_f16(a, b, acc2[tt], 0, 0, 0);
        }
    }

    // epilogue: o = acc + (1-beta)*s (exact fp32 identity); h = elu(o)+o
#pragma unroll
    for (int i = 0; i < 4; ++i) {
        const int lr = w * 16 + lg * 4 + i;
        const int r = row0 + lr;
        if (r >= NN) continue;
        const float dv = dinv[r];
#pragma unroll
        for (int tt = 0; tt < 4; ++tt) {
            const int c = la + 16 * tt;
            const float o = acc2[tt][i] + obeta * sa[lr][c];
            const float h = eluf(o) + o;
            out16[(size_t)r * 64 + c] = __float2half(h * dv);
            if (w32) out32[(size_t)r * 64 + c] = h;
        }
    }
}

// ================= MFMA input GEMM v2 (R6: 71us floor, keep) =================

__global__ __launch_bounds__(256, 6) void mgemm_in_v2(
    const float* __restrict__ A, const __half* __restrict__ wt,
    const float* __restrict__ bias, const float* __restrict__ dinvp,
    float* __restrict__ out32, __half* __restrict__ out16) {
    __shared__ __half sh[64][136];
    const int t = threadIdx.x;
    const int row0 = blockIdx.x * 64;
    const int lane = t & 63;
    const int w = t >> 6;  // wave 0..3 -> rows [w*16, w*16+16)
    const int la = lane & 15, lg = lane >> 4;
    f32x4 acc[4] = {};

#pragma unroll
    for (int kh = 0; kh < 2; ++kh) {
#pragma unroll
        for (int i = 0; i < 8; ++i) {
            const int linear = t + i * 256;  // 0..2047, 32 float4 per row
            const int r = linear >> 5;
            const int q = linear & 31;
            const int grow = row0 + r;
            float4 v = make_float4(0.f, 0.f, 0.f, 0.f);
            if (grow < NN) v = *(const float4*)&A[(size_t)grow * 256 + kh * 128 + q * 4];
            __half2* dst = (__half2*)&sh[r][q * 4];
            dst[0] = __floats2half2_rn(v.x, v.y);
            dst[1] = __floats2half2_rn(v.z, v.w);
        }
        __syncthreads();
        const __half* arow = &sh[w * 16 + la][0];
#pragma unroll
        for (int kc = 0; kc < 4; ++kc) {
            const int k0 = kc * 32 + lg * 8;
            const f16x8 a = *(const f16x8*)&arow[k0];
#pragma unroll
            for (int tt = 0; tt < 4; ++tt) {
                const f16x8 b = *(const f16x8*)&wt[(size_t)(la + 16 * tt) * 256 + kh * 128 + k0];
                acc[tt] = __builtin_amdgcn_mfma_f32_16x16x32_f16(a, b, acc[tt], 0, 0, 0);
            }
        }
        __syncthreads();
    }

#pragma unroll
    for (int i = 0; i < 4; ++i) {
        const int r = row0 + w * 16 + lg * 4 + i;
        if (r >= NN) continue;
        const float dv = dinvp[r];
#pragma unroll
        for (int tt = 0; tt < 4; ++tt) {
            const int c = la + 16 * tt;
            float o = acc[tt][i] + bias[c];
            o = eluf(o);
            out32[(size_t)r * 64 + c] = o;
            out16[(size_t)r * 64 + c] = __float2half(o * dv);
        }
    }
}

// ================= dense GEMM for output layer (R2-proven shape) =================
// MODE 2: out32 = A@B + bias    (KTOT=64)

template <int KTOT, int MODE>
__global__ __launch_bounds__(256, 4) void gemm_v2(const float* __restrict__ A,
                                                  const float* __restrict__ B,
                                                  const float* __restrict__ bias,
                                                  const float* __restrict__ dinvp,
                                                  float* __restrict__ out32,
                                                  __half* __restrict__ out16) {
    __shared__ float ss[64][68];
    __shared__ float ws[64][64];
    const int t = threadIdx.x;
    const int row0 = blockIdx.x * 64;
    const int tx = t & 15, ty = t >> 4;
    float acc[4][4] = {};

    for (int kc = 0; kc < KTOT; kc += 64) {
#pragma unroll
        for (int i = 0; i < 4; ++i) {
            const int linear = t + i * 256;
            const int r = linear >> 4, q = linear & 15;
            const int grow = row0 + r;
            float4 v = make_float4(0.f, 0.f, 0.f, 0.f);
            if (grow < NN) v = *(const float4*)&A[(size_t)grow * KTOT + kc + q * 4];
            *(float4*)&ss[r][q * 4] = v;
        }
#pragma unroll
        for (int i = 0; i < 4; ++i) {
            const int linear = t + i * 256;
            const int r = linear >> 4, q = linear & 15;
            *(float4*)&ws[r][q * 4] = *(const float4*)&B[(size_t)(kc + r) * 64 + q * 4];
        }
        __syncthreads();
#pragma unroll 4
        for (int k = 0; k < 64; k += 4) {
            float4 af[4], bf[4];
            af[0] = *(const float4*)&ss[ty * 4 + 0][k];
            af[1] = *(const float4*)&ss[ty * 4 + 1][k];
            af[2] = *(const float4*)&ss[ty * 4 + 2][k];
            af[3] = *(const float4*)&ss[ty * 4 + 3][k];
            bf[0] = *(const float4*)&ws[k + 0][tx * 4];
            bf[1] = *(const float4*)&ws[k + 1][tx * 4];
            bf[2] = *(const float4*)&ws[k + 2][tx * 4];
            bf[3] = *(const float4*)&ws[k + 3][tx * 4];
            const float* A4 = (const float*)af;
            const float* B4 = (const float*)bf;
#pragma unroll
            for (int i = 0; i < 4; ++i)
#pragma unroll
                for (int kk = 0; kk < 4; ++kk)
#pragma unroll
                    for (int j = 0; j < 4; ++j)
                        acc[i][j] = fmaf(A4[i * 4 + kk], B4[kk * 4 + j], acc[i][j]);
        }
        __syncthreads();
    }

#pragma unroll
    for (int i = 0; i < 4; ++i) {
        const int r = row0 + ty * 4 + i;
        if (r >= NN) continue;
        float4 o;
        float* op = (float*)&o;
#pragma unroll
        for (int j = 0; j < 4; ++j) {
            float xv = acc[i][j] + bias[tx * 4 + j];
            if (MODE == 0) xv = eluf(xv);
            op[j] = xv;
        }
        *(float4*)&out32[(size_t)r * 64 + tx * 4] = o;
        if (MODE == 0) {
            const float dv = dinvp[r];
            __half2* hp = (__half2*)&out16[(size_t)r * 64 + tx * 4];
            hp[0] = __floats2half2_rn(o.x * dv, o.y * dv);
            hp[1] = __floats2half2_rn(o.z * dv, o.w * dv);
        }
    }
}

// ================= launch =================

extern "C" void kernel_launch(void* const* d_in, const int* in_sizes, int n_in, void* d_out,
                              int out_size, void* d_ws, size_t ws_size, hipStream_t stream) {
    const float* x = (const float*)d_in[0];
    const int* ei = (const int*)d_in[1];
    const float* w_in = (const float*)d_in[2];
    const float* b_in = (const float*)d_in[3];
    const float* w_layers = (const float*)d_in[4];
    const float* w_out = (const float*)d_in[5];
    const float* b_out = (const float*)d_in[6];
    float* out = (float*)d_out;

    char* p = (char*)d_ws;
    auto alloc = [&](size_t bytes) -> char* {
        char* r = p;
        p += (bytes + 255) & ~(size_t)255;
        return r;
    };
    int* counts = (int*)alloc((size_t)NN * 4);
    int* bfill = (int*)alloc((size_t)NBUCK * 4);
    int* rp = (int*)alloc((size_t)(NN + 1) * 4);
    int* partial = (int*)alloc(128 * 4);
    float* dinv = (float*)alloc((size_t)NN * 4);
    int* colA = (int*)alloc((size_t)EE * 4);
    unsigned* tmp = (unsigned*)alloc((size_t)EE * 4);         // binned packed edges
    float* x0 = (float*)alloc((size_t)NN * HH * 4);           // fp32 residual
    __half* x0h = (__half*)alloc((size_t)(NN + 1) * HH * 2);  // scaled gather buf A
    __half* hA = (__half*)alloc((size_t)(NN + 1) * HH * 2);   // scaled gather buf B
    float* sbuf = (float*)alloc((size_t)NN * HH * 4);         // final fp32 h (last layer)
    __half* wt = (__half*)alloc((size_t)64 * 256 * 2);        // w_in^T fp16
    __half* btab = (__half*)alloc((size_t)LL * 64 * 64 * 2);  // per-layer (beta*W)^T fp16

    const int* srcA = ei;
    const int* dstA = ei + EE;

    hipMemsetAsync(counts, 0, (size_t)NN * 4, stream);
    hipMemsetAsync(bfill, 0, (size_t)NBUCK * 4, stream);
    init_sent_v2<<<1, 128, 0, stream>>>(x0h, hA);
    conv_w_v1<<<1, 256, 0, stream>>>(w_in, wt);
    conv_wbl_v1<<<LL, 256, 0, stream>>>(w_layers, btab);
    count_edges_v2<<<(EE + 255) / 256, 256, 0, stream>>>(dstA, counts);
    scan_block_v2<<<NBLK, 256, 0, stream>>>(counts, rp, partial, dinv);
    scan_top_v2<<<1, 128, 0, stream>>>(partial);
    scan_add_v2<<<(NN + 1 + 255) / 256, 256, 0, stream>>>(rp, partial);
    bin_edges_v1<<<(EE + BIN_CHUNK - 1) / BIN_CHUNK, 256, 0, stream>>>(srcA, dstA, rp, bfill,
                                                                       tmp);
    unbin_v1<<<NBUCK, 512, 0, stream>>>(tmp, rp, colA);

    // x0 = elu(x @ w_in + b_in);  x0h = half(dinv * x0)   [MFMA]
    mgemm_in_v2<<<(NN + 63) / 64, 256, 0, stream>>>(x, wt, b_in, dinv, x0, x0h);

    for (int l = 0; l < LL; ++l) {
        const float obeta = 1.0f - (float)log(1.0 / (double)(l + 1) + 1.0);
        const __half* hin = (l & 1) ? hA : x0h;  // l=0 reads x0h
        __half* hout = (l & 1) ? x0h : hA;
        fused_layer_v2<<<(NN + 63) / 64, 256, 0, stream>>>(
            rp, colA, dinv, hin, x0, btab + (size_t)l * 64 * 64, obeta, hout, sbuf,
            l == LL - 1);
    }
    gemm_v2<64, 2><<<(NN + 63) / 64, 256, 0, stream>>>(sbuf, w_out, b_out, nullptr, out, nullptr);
}